// Round 1
// baseline (402.490 us; speedup 1.0000x reference)
//
#include <hip/hip_runtime.h>
#include <hip/hip_bf16.h>

#define L_TOK 8192
#define DM 128
#define ED 256
#define NST 16
#define NC 64     // number of scan chunks
#define CL 128    // chunk length (NC*CL == L_TOK)

// ---------------------------------------------------------------------------
// gather patches: xin[l*128 + c*8 + ijk] = ks[c, 2x+i, 2y+j, 2z+k]
__global__ __launch_bounds__(256) void gather_k(const float* __restrict__ ks, float* __restrict__ xin) {
    int i = blockIdx.x * 256 + threadIdx.x;            // < 1048576
    int l = i >> 7, t = i & 127;
    int cc = t >> 3, ijk = t & 7;
    int xg = l >> 8, yg = (l >> 3) & 31, zg = l & 7;
    int i2 = (ijk >> 2) & 1, j2 = (ijk >> 1) & 1, k2 = ijk & 1;
    xin[i] = ks[cc * 65536 + (2 * xg + i2) * 1024 + (2 * yg + j2) * 16 + 2 * zg + k2];
}

// mask pooling -> m[l]
__global__ __launch_bounds__(256) void maskpool_k(const float* __restrict__ mask, float* __restrict__ m) {
    int l = blockIdx.x * 256 + threadIdx.x;            // < 8192
    int xg = l >> 8, yg = (l >> 3) & 31, zg = l & 7;
    float s = 0.f;
    for (int i2 = 0; i2 < 2; ++i2)
        for (int j2 = 0; j2 < 2; ++j2)
            for (int k2 = 0; k2 < 2; ++k2)
                s += mask[(2 * xg + i2) * 1024 + (2 * yg + j2) * 16 + 2 * zg + k2];
    s *= 0.125f;
    m[l] = fminf(fmaxf(s, 0.f), 1.f);
}

// ---------------------------------------------------------------------------
// Generic 64x64-tile fp32 GEMM, 256 threads, 4x4 acc per thread.
// MODE 0: embed   (B K-major = pe_w)  epilogue: +pe_b +cond            -> x (L,128)
// MODE 1: Win     (B N-major ld 512)  epilogue: +bin                   -> xz (L,512)
// MODE 2: Wout    (B N-major ld 128)  epilogue: +bout +h residual      -> hf (L,128)
// MODE 3: unembed (B N-major ld 128)  epilogue: +pu_b +kspace scatter  -> out
// MODE 4: Wx      (B N-major ld 40, col<40 guard)                      -> dbl (L,40)
template <int MODE, int K, int NLD>
__global__ __launch_bounds__(256) void gemm_k(const float* __restrict__ A, const float* __restrict__ B,
                                              float* __restrict__ out,
                                              const float* __restrict__ p0, const float* __restrict__ p1,
                                              const float* __restrict__ p2, const float* __restrict__ p3,
                                              const float* __restrict__ p4) {
    __shared__ float As[64][68];
    __shared__ float Bs[64][68];
    const int tid = threadIdx.x;
    const int tc = tid & 15, tr = tid >> 4;
    const int mb = blockIdx.x * 64, nb = blockIdx.y * 64;
    float acc[4][4] = {};

    for (int k0 = 0; k0 < K; k0 += 64) {
        __syncthreads();
        // A tile: rows (64) x k (64)
        for (int idx = tid; idx < 4096; idx += 256) {
            int r = idx >> 6, kk = idx & 63;
            As[r][kk] = A[(size_t)(mb + r) * K + k0 + kk];
        }
        // B tile
        if (MODE == 0) {  // K-major: B[col][k]
            for (int idx = tid; idx < 4096; idx += 256) {
                int col = idx >> 6, kk = idx & 63;
                Bs[col][kk] = B[(size_t)(nb + col) * K + k0 + kk];
            }
        } else {
            for (int idx = tid; idx < 4096; idx += 256) {
                int col = idx & 63, kk = idx >> 6;
                float v = 0.f;
                if (MODE != 4 || (nb + col) < 40) v = B[(size_t)(k0 + kk) * NLD + nb + col];
                Bs[col][kk] = v;
            }
        }
        __syncthreads();
#pragma unroll 4
        for (int kk = 0; kk < 64; kk += 4) {
            float4 a[4], b[4];
#pragma unroll
            for (int i = 0; i < 4; ++i) a[i] = *(const float4*)&As[4 * tr + i][kk];
#pragma unroll
            for (int j = 0; j < 4; ++j) b[j] = *(const float4*)&Bs[tc + 16 * j][kk];
#pragma unroll
            for (int i = 0; i < 4; ++i)
#pragma unroll
                for (int j = 0; j < 4; ++j)
                    acc[i][j] += a[i].x * b[j].x + a[i].y * b[j].y + a[i].z * b[j].z + a[i].w * b[j].w;
        }
    }

#pragma unroll
    for (int i = 0; i < 4; ++i) {
        int l = mb + 4 * tr + i;
        if (MODE == 0) {
            float rho = (float)l * (1.0f / 8191.0f);
            int band = min(7, (int)(rho * 8.0f));
            float mv = p4[l];
#pragma unroll
            for (int j = 0; j < 4; ++j) {
                int col = nb + tc + 16 * j;
                out[(size_t)l * 128 + col] =
                    acc[i][j] + p0[col] + p1[band * 128 + col] + rho * p2[col] + mv * p3[col];
            }
        } else if (MODE == 1) {
#pragma unroll
            for (int j = 0; j < 4; ++j) {
                int col = nb + tc + 16 * j;
                out[(size_t)l * 512 + col] = acc[i][j] + p0[col];
            }
        } else if (MODE == 2) {
#pragma unroll
            for (int j = 0; j < 4; ++j) {
                int col = nb + tc + 16 * j;
                out[(size_t)l * 128 + col] = acc[i][j] + p0[col] + p1[(size_t)l * 128 + col];
            }
        } else if (MODE == 3) {
            int xg = l >> 8, yg = (l >> 3) & 31, zg = l & 7;
#pragma unroll
            for (int j = 0; j < 4; ++j) {
                int col = nb + tc + 16 * j;
                int c = col >> 3, ijk = col & 7;
                int i2 = (ijk >> 2) & 1, j2 = (ijk >> 1) & 1, k2 = ijk & 1;
                size_t idx = (size_t)((c * 64 + 2 * xg + i2) * 64 + (2 * yg + j2)) * 16 + 2 * zg + k2;
                out[idx] = acc[i][j] + p0[c] + p1[idx];
            }
        } else {  // MODE 4
#pragma unroll
            for (int j = 0; j < 4; ++j) {
                int col = nb + tc + 16 * j;
                if (col < 40) out[(size_t)l * 40 + col] = acc[i][j];
            }
        }
    }
}

// ---------------------------------------------------------------------------
// two stacked LayerNorms over DM=128: h = LN(x; ln), hn = LN(h; fn)
__global__ __launch_bounds__(128) void ln2_k(const float* __restrict__ x,
                                             const float* __restrict__ ln_g, const float* __restrict__ ln_b,
                                             const float* __restrict__ fn_g, const float* __restrict__ fn_b,
                                             float* __restrict__ h, float* __restrict__ hn) {
    int l = blockIdx.x, d = threadIdx.x;
    __shared__ float red[4];
    float v = x[(size_t)l * 128 + d];
    float s = v, s2 = v * v;
#pragma unroll
    for (int o = 32; o > 0; o >>= 1) { s += __shfl_xor(s, o, 64); s2 += __shfl_xor(s2, o, 64); }
    if ((d & 63) == 0) { red[d >> 6] = s; red[2 + (d >> 6)] = s2; }
    __syncthreads();
    float S = red[0] + red[1], S2 = red[2] + red[3];
    float mu = S * (1.f / 128.f);
    float var = S2 * (1.f / 128.f) - mu * mu;
    float rstd = rsqrtf(fmaxf(var, 0.f) + 1e-5f);
    float hv = (v - mu) * rstd * ln_g[d] + ln_b[d];
    h[(size_t)l * 128 + d] = hv;
    __syncthreads();
    s = hv; s2 = hv * hv;
#pragma unroll
    for (int o = 32; o > 0; o >>= 1) { s += __shfl_xor(s, o, 64); s2 += __shfl_xor(s2, o, 64); }
    if ((d & 63) == 0) { red[d >> 6] = s; red[2 + (d >> 6)] = s2; }
    __syncthreads();
    S = red[0] + red[1]; S2 = red[2] + red[3];
    mu = S * (1.f / 128.f);
    var = S2 * (1.f / 128.f) - mu * mu;
    rstd = rsqrtf(fmaxf(var, 0.f) + 1e-5f);
    hn[(size_t)l * 128 + d] = (hv - mu) * rstd * fn_g[d] + fn_b[d];
}

// causal depthwise conv (4 taps) + SiLU; xp = xz[:, :256]
__global__ __launch_bounds__(256) void conv_k(const float* __restrict__ xz, const float* __restrict__ convw,
                                              const float* __restrict__ convb, float* __restrict__ xc) {
    int l = blockIdx.x, e = threadIdx.x;
    float acc = convb[e];
#pragma unroll
    for (int k = 0; k < 4; ++k) {
        int lp = l - 3 + k;
        if (lp >= 0) acc += xz[(size_t)lp * 512 + e] * convw[e * 4 + k];
    }
    float sg = 1.f / (1.f + expf(-acc));
    xc[(size_t)l * 256 + e] = acc * sg;
}

// dt = softplus(dbl[:, :8] @ Wdt + bdt) * s_dt ; Bm, Cm scaled
__global__ __launch_bounds__(256) void dtk_k(const float* __restrict__ dbl, const float* __restrict__ Wdt,
                                             const float* __restrict__ bdt, const float* __restrict__ m,
                                             const float* __restrict__ edt, const float* __restrict__ eB,
                                             const float* __restrict__ eC, const float* __restrict__ wr,
                                             const float* __restrict__ wm,
                                             float* __restrict__ dt, float* __restrict__ Bmo, float* __restrict__ Cmo) {
    int l = blockIdx.x, e = threadIdx.x;
    __shared__ float ds[40];
    __shared__ float sc[3];
    if (e < 40) ds[e] = dbl[(size_t)l * 40 + e];
    if (e == 0) {
        float rho = (float)l * (1.0f / 8191.0f);
        int band = min(7, (int)(rho * 8.0f));
        float mv = m[l];
        sc[0] = 2.0f / (1.f + expf(-(edt[band] + wr[0] * rho + wm[0] * mv)));
        sc[1] = 2.0f / (1.f + expf(-(eB[band] + wr[1] * rho + wm[1] * mv)));
        sc[2] = 2.0f / (1.f + expf(-(eC[band] + wr[2] * rho + wm[2] * mv)));
    }
    __syncthreads();
    float acc = bdt[e];
#pragma unroll
    for (int r = 0; r < 8; ++r) acc += ds[r] * Wdt[r * 256 + e];
    float sp = (acc > 20.f) ? acc : log1pf(expf(acc));
    dt[(size_t)l * 256 + e] = sp * sc[0];
    if (e < 16) Bmo[(size_t)l * 16 + e] = ds[8 + e] * sc[1];
    else if (e < 32) Cmo[(size_t)l * 16 + (e - 16)] = ds[24 + (e - 16)] * sc[2];
}

// ---------------------------------------------------------------------------
// chunked bidirectional linear scan.
// PHASE 0: per-chunk end state (h0=0) -> Hbuf; fwd also chunk dt-sums -> sdt
// PHASE 1: replay with Hinit, emit y = sum_n h*C (16-lane shuffle reduce)
template <int PHASE>
__global__ __launch_bounds__(256) void scan_phase(const float* __restrict__ dt, const float* __restrict__ xc,
                                                  const float* __restrict__ Bm, const float* __restrict__ Cm,
                                                  const float* __restrict__ Alog,
                                                  float* __restrict__ Hbuf, float* __restrict__ sdtbuf,
                                                  const float* __restrict__ Hinit,
                                                  float* __restrict__ yfp, float* __restrict__ ybp) {
    const int c = blockIdx.x, eg = blockIdx.y, dir = blockIdx.z;
    const int tid = threadIdx.x;
    const int ep = tid >> 4, n = tid & 15;
    const int e = eg * 16 + ep;
    const int en = e * 16 + n;
    float Aval = -expf(Alog[en]);
    float A2 = Aval * 1.44269504088896f;   // log2(e)
    float invA = 1.0f / Aval;
    float h = 0.f;
    if (PHASE == 1) h = Hinit[(size_t)(dir * NC + c) * 4096 + en];
    float sdt = 0.f;
    __shared__ float dts[64][16], xcs[64][16], bms[64][16], cms[64][16];
    const int l0 = c * CL;
    for (int t = 0; t < CL / 64; ++t) {
        int ti = (dir == 0) ? t : (CL / 64 - 1 - t);
        int lb = l0 + ti * 64;
        __syncthreads();
        for (int idx = tid; idx < 1024; idx += 256) {
            int ss = idx >> 4, q = idx & 15;
            dts[ss][q] = dt[(size_t)(lb + ss) * 256 + eg * 16 + q];
            xcs[ss][q] = xc[(size_t)(lb + ss) * 256 + eg * 16 + q];
            bms[ss][q] = Bm[(size_t)(lb + ss) * 16 + q];
            if (PHASE == 1) cms[ss][q] = Cm[(size_t)(lb + ss) * 16 + q];
        }
        __syncthreads();
        for (int si = 0; si < 64; ++si) {
            int ss = (dir == 0) ? si : 63 - si;
            float u = dts[ss][ep];
            float a = exp2f(A2 * u);
            float w = xcs[ss][ep] * bms[ss][n] * invA;
            h = a * (h + w) - w;                 // = a*h + (a-1)/A * Bm * xc
            if (PHASE == 0) { if (dir == 0) sdt += u; }
            if (PHASE == 1) {
                float p = h * cms[ss][n];
                p += __shfl_xor(p, 1, 16);
                p += __shfl_xor(p, 2, 16);
                p += __shfl_xor(p, 4, 16);
                p += __shfl_xor(p, 8, 16);
                if (n == 0) {
                    float* yp = (dir == 0) ? yfp : ybp;
                    yp[(size_t)(lb + ss) * 256 + e] = p;
                }
            }
        }
    }
    if (PHASE == 0) {
        Hbuf[(size_t)(dir * NC + c) * 4096 + en] = h;
        if (dir == 0 && n == 0) sdtbuf[c * 256 + e] = sdt;
    }
}

// chunk-level scan: Hinit[dir][c] = running combination of chunk aggregates
__global__ __launch_bounds__(256) void scan_combine(const float* __restrict__ Hbuf, const float* __restrict__ sdtbuf,
                                                    const float* __restrict__ Alog, float* __restrict__ Hinit) {
    int id = blockIdx.x * 256 + threadIdx.x;   // < 8192
    int dir = id >> 12, en = id & 4095, e = en >> 4;
    float A2 = -expf(Alog[en]) * 1.44269504088896f;
    float hi = 0.f;
    if (dir == 0) {
        for (int c = 0; c < NC; ++c) {
            Hinit[(size_t)c * 4096 + en] = hi;
            float P = exp2f(A2 * sdtbuf[c * 256 + e]);
            hi = P * hi + Hbuf[(size_t)c * 4096 + en];
        }
    } else {
        for (int c = NC - 1; c >= 0; --c) {
            Hinit[(size_t)(NC + c) * 4096 + en] = hi;
            float P = exp2f(A2 * sdtbuf[c * 256 + e]);
            hi = P * hi + Hbuf[(size_t)(NC + c) * 4096 + en];
        }
    }
}

// y = (yf + yb + D*xc) * silu(z)
__global__ __launch_bounds__(256) void gate_k(const float* __restrict__ yf, const float* __restrict__ yb,
                                              const float* __restrict__ xc, const float* __restrict__ xz,
                                              const float* __restrict__ Dp, float* __restrict__ y) {
    int i = blockIdx.x * 256 + threadIdx.x;    // < 2097152
    int e = i & 255, l = i >> 8;
    float zv = xz[(size_t)l * 512 + 256 + e];
    float yv = yf[i] + yb[i] + Dp[e] * xc[i];
    y[i] = yv * (zv / (1.f + expf(-zv)));
}

// ---------------------------------------------------------------------------
extern "C" void kernel_launch(void* const* d_in, const int* in_sizes, int n_in,
                              void* d_out, int out_size, void* d_ws, size_t ws_size,
                              hipStream_t stream) {
    const float* ks    = (const float*)d_in[0];
    const float* mask  = (const float*)d_in[1];
    const float* pe_w  = (const float*)d_in[2];
    const float* pe_b  = (const float*)d_in[3];
    const float* pu_w  = (const float*)d_in[4];
    const float* pu_b  = (const float*)d_in[5];
    const float* ln_g  = (const float*)d_in[6];
    const float* ln_b  = (const float*)d_in[7];
    const float* fn_g  = (const float*)d_in[8];
    const float* fn_b  = (const float*)d_in[9];
    const float* cond_band = (const float*)d_in[10];
    const float* cond_rad  = (const float*)d_in[11];
    const float* cond_mask = (const float*)d_in[12];
    const float* Win   = (const float*)d_in[13];
    const float* bin_  = (const float*)d_in[14];
    const float* convw = (const float*)d_in[15];
    const float* convb = (const float*)d_in[16];
    const float* Wx    = (const float*)d_in[17];
    const float* Wdt   = (const float*)d_in[18];
    const float* bdt   = (const float*)d_in[19];
    const float* Alog  = (const float*)d_in[20];
    const float* Dp    = (const float*)d_in[21];
    const float* Wout  = (const float*)d_in[22];
    const float* bout  = (const float*)d_in[23];
    const float* edt   = (const float*)d_in[24];
    const float* eB    = (const float*)d_in[25];
    const float* eC    = (const float*)d_in[26];
    const float* wr    = (const float*)d_in[27];
    const float* wm    = (const float*)d_in[28];
    float* out = (float*)d_out;

    // workspace layout (floats), with lifetime-based reuse
    float* W = (float*)d_ws;
    size_t o = 0;
    float* regA  = W + o; o += 2097152;   // xin (1M) + x (1M); later yf (2M)
    float* regB  = W + o; o += 2097152;   // hn (1M); later yb (2M)
    float* h_    = W + o; o += 1048576;
    float* xz    = W + o; o += 4194304;
    float* xc    = W + o; o += 2097152;
    float* dbl   = W + o; o += 327680;
    float* regC  = W + o; o += 2097152;   // dt; later y
    float* Bm    = W + o; o += 131072;
    float* Cm    = W + o; o += 131072;
    float* Hbuf  = W + o; o += 524288;
    float* sdtb  = W + o; o += 16384;
    float* Hinit = W + o; o += 524288;
    float* hf    = W + o; o += 1048576;
    float* mbuf  = W + o; o += 8192;

    float* xin = regA;
    float* x   = regA + 1048576;
    float* hn  = regB;
    float* dt  = regC;
    float* yf  = regA;
    float* yb  = regB;
    float* y   = regC;

    // 1. gather patches + mask pooling
    gather_k<<<4096, 256, 0, stream>>>(ks, xin);
    maskpool_k<<<32, 256, 0, stream>>>(mask, mbuf);
    // 2. patch embed + cond -> x
    gemm_k<0, 128, 128><<<dim3(128, 2), 256, 0, stream>>>(xin, pe_w, x, pe_b, cond_band, cond_rad, cond_mask, mbuf);
    // 3. double LN -> h, hn
    ln2_k<<<8192, 128, 0, stream>>>(x, ln_g, ln_b, fn_g, fn_b, h_, hn);
    // 4. Win GEMM -> xz
    gemm_k<1, 128, 512><<<dim3(128, 8), 256, 0, stream>>>(hn, Win, xz, bin_, nullptr, nullptr, nullptr, nullptr);
    // 5. conv + silu -> xc
    conv_k<<<8192, 256, 0, stream>>>(xz, convw, convb, xc);
    // 6. Wx GEMM -> dbl
    gemm_k<4, 256, 40><<<dim3(128, 1), 256, 0, stream>>>(xc, Wx, dbl, nullptr, nullptr, nullptr, nullptr, nullptr);
    // 7. dt / Bm / Cm
    dtk_k<<<8192, 256, 0, stream>>>(dbl, Wdt, bdt, mbuf, edt, eB, eC, wr, wm, dt, Bm, Cm);
    // 8. scan phase A (chunk aggregates)
    scan_phase<0><<<dim3(NC, 16, 2), 256, 0, stream>>>(dt, xc, Bm, Cm, Alog, Hbuf, sdtb, nullptr, nullptr, nullptr);
    // 9. chunk-level combine
    scan_combine<<<32, 256, 0, stream>>>(Hbuf, sdtb, Alog, Hinit);
    // 10. scan phase C (replay + y)
    scan_phase<1><<<dim3(NC, 16, 2), 256, 0, stream>>>(dt, xc, Bm, Cm, Alog, nullptr, nullptr, Hinit, yf, yb);
    // 11. gate
    gate_k<<<8192, 256, 0, stream>>>(yf, yb, xc, xz, Dp, y);
    // 12. Wout GEMM + residual -> hf
    gemm_k<2, 256, 128><<<dim3(128, 2), 256, 0, stream>>>(y, Wout, hf, bout, h_, nullptr, nullptr, nullptr);
    // 13. unembed GEMM + residual -> out
    gemm_k<3, 128, 128><<<dim3(128, 2), 256, 0, stream>>>(hf, pu_w, out, pu_b, ks, nullptr, nullptr, nullptr);
}

// Round 2
// 353.950 us; speedup vs baseline: 1.1371x; 1.1371x over previous
//
#include <hip/hip_runtime.h>
#include <hip/hip_bf16.h>

#define L_TOK 8192
#define NCh 256   // scan chunks
#define CLh 32    // chunk length

// ---------------------------------------------------------------------------
// mask pooling -> m[l]
__global__ __launch_bounds__(256) void maskpool_k(const float* __restrict__ mask, float* __restrict__ m) {
    int l = blockIdx.x * 256 + threadIdx.x;            // < 8192
    int xg = l >> 8, yg = (l >> 3) & 31, zg = l & 7;
    float s = 0.f;
    for (int i2 = 0; i2 < 2; ++i2)
        for (int j2 = 0; j2 < 2; ++j2)
            for (int k2 = 0; k2 < 2; ++k2)
                s += mask[(2 * xg + i2) * 1024 + (2 * yg + j2) * 16 + 2 * zg + k2];
    s *= 0.125f;
    m[l] = fminf(fmaxf(s, 0.f), 1.f);
}

// ---------------------------------------------------------------------------
// Tiled fp32 GEMM, 256 threads, TM x 64 tile, TM/16 x 4 acc per thread.
// MODE 0: embed, A = gathered ks patches, B K-major (pe_w); +pe_b +cond -> x
// MODE 1: Win   (B N-major 512) +bin                    -> xz
// MODE 2: Wout  (B N-major 128) +bout +h residual       -> hf
// MODE 3: unembed (B N-major 128) +pu_b +ks, scattered  -> out
// MODE 4: Wx    (B N-major 40, col guard)               -> dbl
template <int MODE, int K, int NLD, int TM>
__global__ __launch_bounds__(256) void gemm_k(const float* __restrict__ A, const float* __restrict__ B,
                                              float* __restrict__ out,
                                              const float* __restrict__ p0, const float* __restrict__ p1,
                                              const float* __restrict__ p2, const float* __restrict__ p3,
                                              const float* __restrict__ p4) {
    constexpr int R = TM / 16;
    __shared__ float As[TM][68];
    __shared__ float Bs[64][68];
    const int tid = threadIdx.x;
    const int tc = tid & 15, tr = tid >> 4;
    const int mb = blockIdx.x * TM, nb = blockIdx.y * 64;
    float acc[R][4] = {};

    for (int k0 = 0; k0 < K; k0 += 64) {
        __syncthreads();
        for (int idx = tid; idx < TM * 64; idx += 256) {
            int r = idx >> 6, kk = idx & 63;
            int l = mb + r, k = k0 + kk;
            if (MODE == 0) {  // gather patch element from kspace
                int cc = k >> 3, ijk = k & 7;
                int xg = l >> 8, yg = (l >> 3) & 31, zg = l & 7;
                int i2 = (ijk >> 2) & 1, j2 = (ijk >> 1) & 1, k2 = ijk & 1;
                As[r][kk] = A[cc * 65536 + (2 * xg + i2) * 1024 + (2 * yg + j2) * 16 + 2 * zg + k2];
            } else {
                As[r][kk] = A[(size_t)l * K + k];
            }
        }
        if (MODE == 0) {  // K-major: B[col][k]
            for (int idx = tid; idx < 4096; idx += 256) {
                int col = idx >> 6, kk = idx & 63;
                Bs[col][kk] = B[(size_t)(nb + col) * K + k0 + kk];
            }
        } else {
            for (int idx = tid; idx < 4096; idx += 256) {
                int col = idx & 63, kk = idx >> 6;
                float v = 0.f;
                if (MODE != 4 || (nb + col) < 40) v = B[(size_t)(k0 + kk) * NLD + nb + col];
                Bs[col][kk] = v;
            }
        }
        __syncthreads();
#pragma unroll 4
        for (int kk = 0; kk < 64; kk += 4) {
            float4 a[R], b[4];
#pragma unroll
            for (int i = 0; i < R; ++i) a[i] = *(const float4*)&As[R * tr + i][kk];
#pragma unroll
            for (int j = 0; j < 4; ++j) b[j] = *(const float4*)&Bs[tc + 16 * j][kk];
#pragma unroll
            for (int i = 0; i < R; ++i)
#pragma unroll
                for (int j = 0; j < 4; ++j)
                    acc[i][j] += a[i].x * b[j].x + a[i].y * b[j].y + a[i].z * b[j].z + a[i].w * b[j].w;
        }
    }

#pragma unroll
    for (int i = 0; i < R; ++i) {
        int l = mb + R * tr + i;
        if (MODE == 0) {
            float rho = (float)l * (1.0f / 8191.0f);
            int band = min(7, (int)(rho * 8.0f));
            float mv = p4[l];
#pragma unroll
            for (int j = 0; j < 4; ++j) {
                int col = nb + tc + 16 * j;
                out[(size_t)l * 128 + col] =
                    acc[i][j] + p0[col] + p1[band * 128 + col] + rho * p2[col] + mv * p3[col];
            }
        } else if (MODE == 1) {
#pragma unroll
            for (int j = 0; j < 4; ++j) {
                int col = nb + tc + 16 * j;
                out[(size_t)l * 512 + col] = acc[i][j] + p0[col];
            }
        } else if (MODE == 2) {
#pragma unroll
            for (int j = 0; j < 4; ++j) {
                int col = nb + tc + 16 * j;
                out[(size_t)l * 128 + col] = acc[i][j] + p0[col] + p1[(size_t)l * 128 + col];
            }
        } else if (MODE == 3) {
            int xg = l >> 8, yg = (l >> 3) & 31, zg = l & 7;
#pragma unroll
            for (int j = 0; j < 4; ++j) {
                int col = nb + tc + 16 * j;
                int c = col >> 3, ijk = col & 7;
                int i2 = (ijk >> 2) & 1, j2 = (ijk >> 1) & 1, k2 = ijk & 1;
                size_t idx = (size_t)((c * 64 + 2 * xg + i2) * 64 + (2 * yg + j2)) * 16 + 2 * zg + k2;
                out[idx] = acc[i][j] + p0[c] + p1[idx];
            }
        } else {  // MODE 4
#pragma unroll
            for (int j = 0; j < 4; ++j) {
                int col = nb + tc + 16 * j;
                if (col < 40) out[(size_t)l * 40 + col] = acc[i][j];
            }
        }
    }
}

// ---------------------------------------------------------------------------
// two stacked LayerNorms over DM=128
__global__ __launch_bounds__(128) void ln2_k(const float* __restrict__ x,
                                             const float* __restrict__ ln_g, const float* __restrict__ ln_b,
                                             const float* __restrict__ fn_g, const float* __restrict__ fn_b,
                                             float* __restrict__ h, float* __restrict__ hn) {
    int l = blockIdx.x, d = threadIdx.x;
    __shared__ float red[4];
    float v = x[(size_t)l * 128 + d];
    float s = v, s2 = v * v;
#pragma unroll
    for (int o = 32; o > 0; o >>= 1) { s += __shfl_xor(s, o, 64); s2 += __shfl_xor(s2, o, 64); }
    if ((d & 63) == 0) { red[d >> 6] = s; red[2 + (d >> 6)] = s2; }
    __syncthreads();
    float S = red[0] + red[1], S2 = red[2] + red[3];
    float mu = S * (1.f / 128.f);
    float var = S2 * (1.f / 128.f) - mu * mu;
    float rstd = rsqrtf(fmaxf(var, 0.f) + 1e-5f);
    float hv = (v - mu) * rstd * ln_g[d] + ln_b[d];
    h[(size_t)l * 128 + d] = hv;
    __syncthreads();
    s = hv; s2 = hv * hv;
#pragma unroll
    for (int o = 32; o > 0; o >>= 1) { s += __shfl_xor(s, o, 64); s2 += __shfl_xor(s2, o, 64); }
    if ((d & 63) == 0) { red[d >> 6] = s; red[2 + (d >> 6)] = s2; }
    __syncthreads();
    S = red[0] + red[1]; S2 = red[2] + red[3];
    mu = S * (1.f / 128.f);
    var = S2 * (1.f / 128.f) - mu * mu;
    rstd = rsqrtf(fmaxf(var, 0.f) + 1e-5f);
    hn[(size_t)l * 128 + d] = (hv - mu) * rstd * fn_g[d] + fn_b[d];
}

// causal depthwise conv (4 taps) + SiLU
__global__ __launch_bounds__(256) void conv_k(const float* __restrict__ xz, const float* __restrict__ convw,
                                              const float* __restrict__ convb, float* __restrict__ xc) {
    int l = blockIdx.x, e = threadIdx.x;
    float acc = convb[e];
#pragma unroll
    for (int k = 0; k < 4; ++k) {
        int lp = l - 3 + k;
        if (lp >= 0) acc += xz[(size_t)lp * 512 + e] * convw[e * 4 + k];
    }
    float sg = 1.f / (1.f + expf(-acc));
    xc[(size_t)l * 256 + e] = acc * sg;
}

// dt = softplus(dbl[:, :8] @ Wdt + bdt) * s_dt ; Bm, Cm scaled
__global__ __launch_bounds__(256) void dtk_k(const float* __restrict__ dbl, const float* __restrict__ Wdt,
                                             const float* __restrict__ bdt, const float* __restrict__ m,
                                             const float* __restrict__ edt, const float* __restrict__ eB,
                                             const float* __restrict__ eC, const float* __restrict__ wr,
                                             const float* __restrict__ wm,
                                             float* __restrict__ dt, float* __restrict__ Bmo, float* __restrict__ Cmo) {
    int l = blockIdx.x, e = threadIdx.x;
    __shared__ float ds[40];
    __shared__ float sc[3];
    if (e < 40) ds[e] = dbl[(size_t)l * 40 + e];
    if (e == 0) {
        float rho = (float)l * (1.0f / 8191.0f);
        int band = min(7, (int)(rho * 8.0f));
        float mv = m[l];
        sc[0] = 2.0f / (1.f + expf(-(edt[band] + wr[0] * rho + wm[0] * mv)));
        sc[1] = 2.0f / (1.f + expf(-(eB[band] + wr[1] * rho + wm[1] * mv)));
        sc[2] = 2.0f / (1.f + expf(-(eC[band] + wr[2] * rho + wm[2] * mv)));
    }
    __syncthreads();
    float acc = bdt[e];
#pragma unroll
    for (int r = 0; r < 8; ++r) acc += ds[r] * Wdt[r * 256 + e];
    float sp = (acc > 20.f) ? acc : log1pf(expf(acc));
    dt[(size_t)l * 256 + e] = sp * sc[0];
    if (e < 16) Bmo[(size_t)l * 16 + e] = ds[8 + e] * sc[1];
    else if (e < 32) Cmo[(size_t)l * 16 + (e - 16)] = ds[24 + (e - 16)] * sc[2];
}

// ---------------------------------------------------------------------------
// scan, one lane per channel e, h[16] in registers.
// PHASE 0: chunk-local end states -> Hb, fwd chunk dt-sums -> sdtb
// PHASE 1: replay from Hb (prefix states written by combine), emit yf/yb
template <int PHASE>
__global__ __launch_bounds__(256) void scan_k(const float* __restrict__ dt, const float* __restrict__ xc,
                                              const float* __restrict__ Bm, const float* __restrict__ Cm,
                                              const float* __restrict__ Alog,
                                              float* __restrict__ Hb, float* __restrict__ sdtb,
                                              float* __restrict__ yf, float* __restrict__ yb) {
    const int c = blockIdx.x, dir = blockIdx.y, e = threadIdx.x;
    __shared__ float bms[CLh][16];
    __shared__ float cms[CLh][16];
    for (int idx = e; idx < CLh * 16; idx += 256) {
        bms[idx >> 4][idx & 15] = Bm[c * (CLh * 16) + idx];
        if (PHASE == 1) cms[idx >> 4][idx & 15] = Cm[c * (CLh * 16) + idx];
    }
    float A2[16], iv[16], h[16];
#pragma unroll
    for (int n = 0; n < 16; ++n) {
        float ea = expf(Alog[e * 16 + n]);
        A2[n] = -ea * 1.44269504088896f;
        iv[n] = -1.0f / ea;                 // 1/A
    }
    const size_t hofs = (size_t)(dir * NCh + c) * 4096 + e * 16;
    if (PHASE == 0) {
#pragma unroll
        for (int n = 0; n < 16; ++n) h[n] = 0.f;
    } else {
#pragma unroll
        for (int j = 0; j < 4; ++j) {
            float4 hv = *(const float4*)&Hb[hofs + 4 * j];
            h[4 * j] = hv.x; h[4 * j + 1] = hv.y; h[4 * j + 2] = hv.z; h[4 * j + 3] = hv.w;
        }
    }
    __syncthreads();
    const int base = c * CLh;
    float sdt = 0.f;
    int p0i = dir ? (CLh - 1) : 0;
    float u_n = dt[(size_t)(base + p0i) * 256 + e];
    float x_n = xc[(size_t)(base + p0i) * 256 + e];
    for (int s = 0; s < CLh; ++s) {
        int p = dir ? (CLh - 1 - s) : s;
        float u = u_n, xv = x_n;
        if (s + 1 < CLh) {
            int p2 = dir ? (CLh - 2 - s) : (s + 1);
            u_n = dt[(size_t)(base + p2) * 256 + e];
            x_n = xc[(size_t)(base + p2) * 256 + e];
        }
        union { float4 v[4]; float f[16]; } bb, cc;
        const float4* bp = (const float4*)&bms[p][0];
        bb.v[0] = bp[0]; bb.v[1] = bp[1]; bb.v[2] = bp[2]; bb.v[3] = bp[3];
        if (PHASE == 1) {
            const float4* cp = (const float4*)&cms[p][0];
            cc.v[0] = cp[0]; cc.v[1] = cp[1]; cc.v[2] = cp[2]; cc.v[3] = cp[3];
        }
        float y = 0.f;
#pragma unroll
        for (int n = 0; n < 16; ++n) {
            float a = exp2f(A2[n] * u);
            float w = xv * bb.f[n] * iv[n];
            float t = h[n] + w;
            h[n] = a * t - w;
            if (PHASE == 1) y += h[n] * cc.f[n];
        }
        if (PHASE == 0) sdt += u;
        if (PHASE == 1) {
            float* yp = dir ? yb : yf;
            yp[(size_t)(base + p) * 256 + e] = y;
        }
    }
    if (PHASE == 0) {
#pragma unroll
        for (int j = 0; j < 4; ++j) {
            float4 hv = make_float4(h[4 * j], h[4 * j + 1], h[4 * j + 2], h[4 * j + 3]);
            *(float4*)&Hb[hofs + 4 * j] = hv;
        }
        if (dir == 0) sdtb[c * 256 + e] = sdt;
    }
}

// chunk-level scan, in place: Hb[c] <- prefix state entering chunk c
__global__ __launch_bounds__(256) void combine_k(float* __restrict__ Hb, const float* __restrict__ sdtb,
                                                 const float* __restrict__ Alog) {
    int id = blockIdx.x * 256 + threadIdx.x;   // < 8192
    int dir = id >> 12, en = id & 4095, e = en >> 4;
    float A2 = -expf(Alog[en]) * 1.44269504088896f;
    float hi = 0.f;
    for (int g = 0; g < NCh / 8; ++g) {
        float Pv[8], qv[8];
#pragma unroll
        for (int j = 0; j < 8; ++j) {
            int c = dir ? (NCh - 1 - (g * 8 + j)) : (g * 8 + j);
            Pv[j] = sdtb[c * 256 + e];
            qv[j] = Hb[(size_t)(dir * NCh + c) * 4096 + en];
        }
#pragma unroll
        for (int j = 0; j < 8; ++j) {
            int c = dir ? (NCh - 1 - (g * 8 + j)) : (g * 8 + j);
            float P = exp2f(A2 * Pv[j]);
            Hb[(size_t)(dir * NCh + c) * 4096 + en] = hi;
            hi = P * hi + qv[j];
        }
    }
}

// y = (yf + yb + D*xc) * silu(z)
__global__ __launch_bounds__(256) void gate_k(const float* __restrict__ yf, const float* __restrict__ yb,
                                              const float* __restrict__ xc, const float* __restrict__ xz,
                                              const float* __restrict__ Dp, float* __restrict__ y) {
    int i = blockIdx.x * 256 + threadIdx.x;    // < 2097152
    int e = i & 255, l = i >> 8;
    float zv = xz[(size_t)l * 512 + 256 + e];
    float yv = yf[i] + yb[i] + Dp[e] * xc[i];
    y[i] = yv * (zv / (1.f + expf(-zv)));
}

// ---------------------------------------------------------------------------
extern "C" void kernel_launch(void* const* d_in, const int* in_sizes, int n_in,
                              void* d_out, int out_size, void* d_ws, size_t ws_size,
                              hipStream_t stream) {
    const float* ks    = (const float*)d_in[0];
    const float* mask  = (const float*)d_in[1];
    const float* pe_w  = (const float*)d_in[2];
    const float* pe_b  = (const float*)d_in[3];
    const float* pu_w  = (const float*)d_in[4];
    const float* pu_b  = (const float*)d_in[5];
    const float* ln_g  = (const float*)d_in[6];
    const float* ln_b  = (const float*)d_in[7];
    const float* fn_g  = (const float*)d_in[8];
    const float* fn_b  = (const float*)d_in[9];
    const float* cond_band = (const float*)d_in[10];
    const float* cond_rad  = (const float*)d_in[11];
    const float* cond_mask = (const float*)d_in[12];
    const float* Win   = (const float*)d_in[13];
    const float* bin_  = (const float*)d_in[14];
    const float* convw = (const float*)d_in[15];
    const float* convb = (const float*)d_in[16];
    const float* Wx    = (const float*)d_in[17];
    const float* Wdt   = (const float*)d_in[18];
    const float* bdt   = (const float*)d_in[19];
    const float* Alog  = (const float*)d_in[20];
    const float* Dp    = (const float*)d_in[21];
    const float* Wout  = (const float*)d_in[22];
    const float* bout  = (const float*)d_in[23];
    const float* edt   = (const float*)d_in[24];
    const float* eB    = (const float*)d_in[25];
    const float* eC    = (const float*)d_in[26];
    const float* wr    = (const float*)d_in[27];
    const float* wm    = (const float*)d_in[28];
    float* out = (float*)d_out;

    // workspace layout (floats), lifetime-reused; total ~64 MB
    float* W = (float*)d_ws;
    size_t o = 0;
    float* regA = W + o; o += 2097152;   // x -> yf -> hf
    float* regB = W + o; o += 2097152;   // hn / dbl(+1M) -> yb
    float* h_   = W + o; o += 1048576;
    float* xz   = W + o; o += 4194304;
    float* xc   = W + o; o += 2097152;
    float* dt   = W + o; o += 2097152;
    float* Bm   = W + o; o += 131072;
    float* Cm   = W + o; o += 131072;
    float* Hb   = W + o; o += 2097152;   // chunk states -> y
    float* sdtb = W + o; o += 65536;
    float* mbuf = W + o; o += 8192;

    float* x   = regA;
    float* hn  = regB;
    float* dbl = regB + 1048576;
    float* yf  = regA;
    float* yb  = regB;
    float* hf  = regA;
    float* y   = Hb;

    maskpool_k<<<32, 256, 0, stream>>>(mask, mbuf);
    // embed (gather fused) + cond -> x
    gemm_k<0, 128, 128, 32><<<dim3(256, 2), 256, 0, stream>>>(ks, pe_w, x, pe_b, cond_band, cond_rad, cond_mask, mbuf);
    // double LN
    ln2_k<<<8192, 128, 0, stream>>>(x, ln_g, ln_b, fn_g, fn_b, h_, hn);
    // Win
    gemm_k<1, 128, 512, 64><<<dim3(128, 8), 256, 0, stream>>>(hn, Win, xz, bin_, nullptr, nullptr, nullptr, nullptr);
    // conv + silu
    conv_k<<<8192, 256, 0, stream>>>(xz, convw, convb, xc);
    // Wx
    gemm_k<4, 256, 40, 32><<<dim3(256, 1), 256, 0, stream>>>(xc, Wx, dbl, nullptr, nullptr, nullptr, nullptr, nullptr);
    // dt / Bm / Cm
    dtk_k<<<8192, 256, 0, stream>>>(dbl, Wdt, bdt, mbuf, edt, eB, eC, wr, wm, dt, Bm, Cm);
    // scan
    scan_k<0><<<dim3(NCh, 2), 256, 0, stream>>>(dt, xc, Bm, Cm, Alog, Hb, sdtb, nullptr, nullptr);
    combine_k<<<32, 256, 0, stream>>>(Hb, sdtb, Alog);
    scan_k<1><<<dim3(NCh, 2), 256, 0, stream>>>(dt, xc, Bm, Cm, Alog, Hb, sdtb, yf, yb);
    // gate
    gate_k<<<8192, 256, 0, stream>>>(yf, yb, xc, xz, Dp, y);
    // Wout + residual
    gemm_k<2, 256, 128, 32><<<dim3(256, 2), 256, 0, stream>>>(y, Wout, hf, bout, h_, nullptr, nullptr, nullptr);
    // unembed + residual -> out
    gemm_k<3, 128, 128, 32><<<dim3(256, 2), 256, 0, stream>>>(hf, pu_w, out, pu_b, ks, nullptr, nullptr, nullptr);
}

// Round 3
// 295.364 us; speedup vs baseline: 1.3627x; 1.1984x over previous
//
#include <hip/hip_runtime.h>
#include <hip/hip_bf16.h>

#define L_TOK 8192
#define NCh 256   // scan chunks
#define CLh 32    // chunk length

typedef short bf16x8 __attribute__((ext_vector_type(8)));
typedef float f32x4 __attribute__((ext_vector_type(4)));

static __device__ __forceinline__ ushort f2bf(float x) {
    union { float f; uint u; } v; v.f = x;
    uint r = v.u + 0x7fffu + ((v.u >> 16) & 1u);
    return (ushort)(r >> 16);
}
static __device__ __forceinline__ float bf2f(ushort h) {
    union { float f; uint u; } v; v.u = ((uint)h) << 16;
    return v.f;
}
static __device__ __forceinline__ void f2hl(float x, ushort* hi, ushort* lo) {
    ushort h = f2bf(x);
    *hi = h;
    *lo = f2bf(x - bf2f(h));
}

// ---------------------------------------------------------------------------
// mask pooling -> m[l]
__global__ __launch_bounds__(256) void maskpool_k(const float* __restrict__ mask, float* __restrict__ m) {
    int l = blockIdx.x * 256 + threadIdx.x;            // < 8192
    int xg = l >> 8, yg = (l >> 3) & 31, zg = l & 7;
    float s = 0.f;
    for (int i2 = 0; i2 < 2; ++i2)
        for (int j2 = 0; j2 < 2; ++j2)
            for (int k2 = 0; k2 < 2; ++k2)
                s += mask[(2 * xg + i2) * 1024 + (2 * yg + j2) * 16 + 2 * zg + k2];
    s *= 0.125f;
    m[l] = fminf(fmaxf(s, 0.f), 1.f);
}

// one-time weight prep: convert (and transpose where needed) to K-major bf16 hi/lo
// layout in wH/wL: [0,16384): pe_w [n][k]   (already K-major)
//                  [16384,81920): Win^T [n=512][k=128]
//                  [81920,98304): Wx^T  [n=64][k=256]  (n>=40 zero)
//                  [98304,131072): Wout^T [n=128][k=256]
//                  [131072,147456): pu^T  [n=128][k=128]
__global__ __launch_bounds__(256) void prep_w(const float* __restrict__ pe_w, const float* __restrict__ Win,
                                              const float* __restrict__ Wx, const float* __restrict__ Wout,
                                              const float* __restrict__ pu_w,
                                              ushort* __restrict__ wH, ushort* __restrict__ wL) {
    int i = blockIdx.x * 256 + threadIdx.x;
    if (i >= 147456) return;
    float v;
    if (i < 16384) {
        v = pe_w[i];
    } else if (i < 81920) {
        int j = i - 16384; int n = j >> 7, k = j & 127;
        v = Win[k * 512 + n];
    } else if (i < 98304) {
        int j = i - 81920; int n = j >> 8, k = j & 255;
        v = (n < 40) ? Wx[k * 40 + n] : 0.f;
    } else if (i < 131072) {
        int j = i - 98304; int n = j >> 8, k = j & 255;
        v = Wout[k * 128 + n];
    } else {
        int j = i - 131072; int n = j >> 7, k = j & 127;
        v = pu_w[k * 128 + n];
    }
    ushort h, lo; f2hl(v, &h, &lo);
    wH[i] = h; wL[i] = lo;
}

// gather patches -> bf16 hi/lo A-matrix [l][128]
__global__ __launch_bounds__(256) void gather_k(const float* __restrict__ ks,
                                                ushort* __restrict__ xH, ushort* __restrict__ xL) {
    int i = blockIdx.x * 256 + threadIdx.x;            // < 1048576
    int l = i >> 7, t = i & 127;
    int cc = t >> 3, ijk = t & 7;
    int xg = l >> 8, yg = (l >> 3) & 31, zg = l & 7;
    int i2 = (ijk >> 2) & 1, j2 = (ijk >> 1) & 1, k2 = ijk & 1;
    float v = ks[cc * 65536 + (2 * xg + i2) * 1024 + (2 * yg + j2) * 16 + 2 * zg + k2];
    ushort h, lo; f2hl(v, &h, &lo);
    xH[i] = h; xL[i] = lo;
}

// ---------------------------------------------------------------------------
// MFMA GEMM: C[M,N] = A[M,K] * B[N,K]^T with A,B in bf16 hi/lo (3-mfma split fp32).
// Tile 128x64, 256 threads (4 waves as 2x2), wave computes 64x32.
// MODE 0: embed  +pe_b +cond -> x fp32
// MODE 1: Win    +bin        -> xz fp32 (ld 512)
// MODE 2: Wout   +bout +h_   -> hf bf16 hi/lo
// MODE 3: unembed +pu_b +ks  -> out fp32 scattered
// MODE 4: Wx (col<40)        -> dbl fp32 (ld 40)
template <int MODE, int K>
__global__ __launch_bounds__(256) void mgemm_k(const ushort* __restrict__ Ah, const ushort* __restrict__ Al,
                                               const ushort* __restrict__ Bh, const ushort* __restrict__ Bl,
                                               float* __restrict__ outF,
                                               ushort* __restrict__ outH, ushort* __restrict__ outL,
                                               const float* __restrict__ p0, const float* __restrict__ p1,
                                               const float* __restrict__ p2, const float* __restrict__ p3,
                                               const float* __restrict__ p4) {
    __shared__ ushort AsH[128][72], AsL[128][72];
    __shared__ ushort BsH[64][72], BsL[64][72];
    const int tid = threadIdx.x;
    const int lane = tid & 63, wave = tid >> 6;
    const int wm = wave & 1, wn = wave >> 1;
    const int ln = lane & 15, q = lane >> 4;
    const int mb = blockIdx.x * 128, nb = blockIdx.y * 64;

    f32x4 acc[4][2];
#pragma unroll
    for (int rb = 0; rb < 4; ++rb)
#pragma unroll
        for (int cb = 0; cb < 2; ++cb)
            acc[rb][cb] = (f32x4){0.f, 0.f, 0.f, 0.f};

    for (int kc = 0; kc < K; kc += 64) {
        __syncthreads();
        for (int u = tid; u < 1024; u += 256) {
            int r = u >> 3, g = u & 7;
            size_t go = (size_t)(mb + r) * K + kc + g * 8;
            *(uint4*)&AsH[r][g * 8] = *(const uint4*)&Ah[go];
            *(uint4*)&AsL[r][g * 8] = *(const uint4*)&Al[go];
        }
        for (int u = tid; u < 512; u += 256) {
            int r = u >> 3, g = u & 7;
            size_t go = (size_t)(nb + r) * K + kc + g * 8;
            *(uint4*)&BsH[r][g * 8] = *(const uint4*)&Bh[go];
            *(uint4*)&BsL[r][g * 8] = *(const uint4*)&Bl[go];
        }
        __syncthreads();
#pragma unroll
        for (int ks = 0; ks < 64; ks += 32) {
            const int kk = ks + q * 8;
            bf16x8 ah[4], al[4], bh[2], bl[2];
#pragma unroll
            for (int rb = 0; rb < 4; ++rb) {
                ah[rb] = *(const bf16x8*)&AsH[wm * 64 + rb * 16 + ln][kk];
                al[rb] = *(const bf16x8*)&AsL[wm * 64 + rb * 16 + ln][kk];
            }
#pragma unroll
            for (int cb = 0; cb < 2; ++cb) {
                bh[cb] = *(const bf16x8*)&BsH[wn * 32 + cb * 16 + ln][kk];
                bl[cb] = *(const bf16x8*)&BsL[wn * 32 + cb * 16 + ln][kk];
            }
#pragma unroll
            for (int rb = 0; rb < 4; ++rb)
#pragma unroll
                for (int cb = 0; cb < 2; ++cb) {
                    acc[rb][cb] = __builtin_amdgcn_mfma_f32_16x16x32_bf16(ah[rb], bh[cb], acc[rb][cb], 0, 0, 0);
                    acc[rb][cb] = __builtin_amdgcn_mfma_f32_16x16x32_bf16(ah[rb], bl[cb], acc[rb][cb], 0, 0, 0);
                    acc[rb][cb] = __builtin_amdgcn_mfma_f32_16x16x32_bf16(al[rb], bh[cb], acc[rb][cb], 0, 0, 0);
                }
        }
    }

#pragma unroll
    for (int rb = 0; rb < 4; ++rb) {
#pragma unroll
        for (int cb = 0; cb < 2; ++cb) {
#pragma unroll
            for (int r = 0; r < 4; ++r) {
                int l = mb + wm * 64 + rb * 16 + q * 4 + r;
                int col = nb + wn * 32 + cb * 16 + ln;
                float v = acc[rb][cb][r];
                if (MODE == 0) {
                    float rho = (float)l * (1.0f / 8191.0f);
                    int band = min(7, (int)(rho * 8.0f));
                    outF[(size_t)l * 128 + col] =
                        v + p0[col] + p1[band * 128 + col] + rho * p2[col] + p4[l] * p3[col];
                } else if (MODE == 1) {
                    outF[(size_t)l * 512 + col] = v + p0[col];
                } else if (MODE == 2) {
                    float o = v + p0[col] + p1[(size_t)l * 128 + col];
                    ushort h, lo; f2hl(o, &h, &lo);
                    outH[(size_t)l * 128 + col] = h;
                    outL[(size_t)l * 128 + col] = lo;
                } else if (MODE == 3) {
                    int xg = l >> 8, yg = (l >> 3) & 31, zg = l & 7;
                    int c = col >> 3, ijk = col & 7;
                    int i2 = (ijk >> 2) & 1, j2 = (ijk >> 1) & 1, k2 = ijk & 1;
                    size_t idx = (size_t)((c * 64 + 2 * xg + i2) * 64 + (2 * yg + j2)) * 16 + 2 * zg + k2;
                    outF[idx] = v + p0[c] + p1[idx];
                } else {  // MODE 4
                    if (col < 40) outF[(size_t)l * 40 + col] = v;
                }
            }
        }
    }
}

// ---------------------------------------------------------------------------
// two stacked LayerNorms over DM=128; hn emitted as bf16 hi/lo for the Win GEMM
__global__ __launch_bounds__(128) void ln2_k(const float* __restrict__ x,
                                             const float* __restrict__ ln_g, const float* __restrict__ ln_b,
                                             const float* __restrict__ fn_g, const float* __restrict__ fn_b,
                                             float* __restrict__ h,
                                             ushort* __restrict__ hnH, ushort* __restrict__ hnL) {
    int l = blockIdx.x, d = threadIdx.x;
    __shared__ float red[4];
    float v = x[(size_t)l * 128 + d];
    float s = v, s2 = v * v;
#pragma unroll
    for (int o = 32; o > 0; o >>= 1) { s += __shfl_xor(s, o, 64); s2 += __shfl_xor(s2, o, 64); }
    if ((d & 63) == 0) { red[d >> 6] = s; red[2 + (d >> 6)] = s2; }
    __syncthreads();
    float S = red[0] + red[1], S2 = red[2] + red[3];
    float mu = S * (1.f / 128.f);
    float var = S2 * (1.f / 128.f) - mu * mu;
    float rstd = rsqrtf(fmaxf(var, 0.f) + 1e-5f);
    float hv = (v - mu) * rstd * ln_g[d] + ln_b[d];
    h[(size_t)l * 128 + d] = hv;
    __syncthreads();
    s = hv; s2 = hv * hv;
#pragma unroll
    for (int o = 32; o > 0; o >>= 1) { s += __shfl_xor(s, o, 64); s2 += __shfl_xor(s2, o, 64); }
    if ((d & 63) == 0) { red[d >> 6] = s; red[2 + (d >> 6)] = s2; }
    __syncthreads();
    S = red[0] + red[1]; S2 = red[2] + red[3];
    mu = S * (1.f / 128.f);
    var = S2 * (1.f / 128.f) - mu * mu;
    rstd = rsqrtf(fmaxf(var, 0.f) + 1e-5f);
    float o2 = (hv - mu) * rstd * fn_g[d] + fn_b[d];
    ushort hh, ll; f2hl(o2, &hh, &ll);
    hnH[(size_t)l * 128 + d] = hh;
    hnL[(size_t)l * 128 + d] = ll;
}

// causal depthwise conv (4 taps) + SiLU; fp32 for scan/gate + bf16 hi/lo for Wx GEMM
__global__ __launch_bounds__(256) void conv_k(const float* __restrict__ xz, const float* __restrict__ convw,
                                              const float* __restrict__ convb, float* __restrict__ xc,
                                              ushort* __restrict__ xcH, ushort* __restrict__ xcL) {
    int l = blockIdx.x, e = threadIdx.x;
    float acc = convb[e];
#pragma unroll
    for (int k = 0; k < 4; ++k) {
        int lp = l - 3 + k;
        if (lp >= 0) acc += xz[(size_t)lp * 512 + e] * convw[e * 4 + k];
    }
    float sg = 1.f / (1.f + expf(-acc));
    float v = acc * sg;
    xc[(size_t)l * 256 + e] = v;
    ushort h, lo; f2hl(v, &h, &lo);
    xcH[(size_t)l * 256 + e] = h;
    xcL[(size_t)l * 256 + e] = lo;
}

// dt = softplus(dbl[:, :8] @ Wdt + bdt) * s_dt ; Bm, Cm scaled
__global__ __launch_bounds__(256) void dtk_k(const float* __restrict__ dbl, const float* __restrict__ Wdt,
                                             const float* __restrict__ bdt, const float* __restrict__ m,
                                             const float* __restrict__ edt, const float* __restrict__ eB,
                                             const float* __restrict__ eC, const float* __restrict__ wr,
                                             const float* __restrict__ wm,
                                             float* __restrict__ dt, float* __restrict__ Bmo, float* __restrict__ Cmo) {
    int l = blockIdx.x, e = threadIdx.x;
    __shared__ float ds[40];
    __shared__ float sc[3];
    if (e < 40) ds[e] = dbl[(size_t)l * 40 + e];
    if (e == 0) {
        float rho = (float)l * (1.0f / 8191.0f);
        int band = min(7, (int)(rho * 8.0f));
        float mv = m[l];
        sc[0] = 2.0f / (1.f + expf(-(edt[band] + wr[0] * rho + wm[0] * mv)));
        sc[1] = 2.0f / (1.f + expf(-(eB[band] + wr[1] * rho + wm[1] * mv)));
        sc[2] = 2.0f / (1.f + expf(-(eC[band] + wr[2] * rho + wm[2] * mv)));
    }
    __syncthreads();
    float acc = bdt[e];
#pragma unroll
    for (int r = 0; r < 8; ++r) acc += ds[r] * Wdt[r * 256 + e];
    float sp = (acc > 20.f) ? acc : log1pf(expf(acc));
    dt[(size_t)l * 256 + e] = sp * sc[0];
    if (e < 16) Bmo[(size_t)l * 16 + e] = ds[8 + e] * sc[1];
    else if (e < 32) Cmo[(size_t)l * 16 + (e - 16)] = ds[24 + (e - 16)] * sc[2];
}

// ---------------------------------------------------------------------------
// scan, one lane per channel e, h[16] in registers.
template <int PHASE>
__global__ __launch_bounds__(256) void scan_k(const float* __restrict__ dt, const float* __restrict__ xc,
                                              const float* __restrict__ Bm, const float* __restrict__ Cm,
                                              const float* __restrict__ Alog,
                                              float* __restrict__ Hb, float* __restrict__ sdtb,
                                              float* __restrict__ yf, float* __restrict__ yb) {
    const int c = blockIdx.x, dir = blockIdx.y, e = threadIdx.x;
    __shared__ float bms[CLh][16];
    __shared__ float cms[CLh][16];
    for (int idx = e; idx < CLh * 16; idx += 256) {
        bms[idx >> 4][idx & 15] = Bm[c * (CLh * 16) + idx];
        if (PHASE == 1) cms[idx >> 4][idx & 15] = Cm[c * (CLh * 16) + idx];
    }
    float A2[16], iv[16], h[16];
#pragma unroll
    for (int n = 0; n < 16; ++n) {
        float ea = expf(Alog[e * 16 + n]);
        A2[n] = -ea * 1.44269504088896f;
        iv[n] = -1.0f / ea;
    }
    const size_t hofs = (size_t)(dir * NCh + c) * 4096 + e * 16;
    if (PHASE == 0) {
#pragma unroll
        for (int n = 0; n < 16; ++n) h[n] = 0.f;
    } else {
#pragma unroll
        for (int j = 0; j < 4; ++j) {
            float4 hv = *(const float4*)&Hb[hofs + 4 * j];
            h[4 * j] = hv.x; h[4 * j + 1] = hv.y; h[4 * j + 2] = hv.z; h[4 * j + 3] = hv.w;
        }
    }
    __syncthreads();
    const int base = c * CLh;
    float sdt = 0.f;
    int p0i = dir ? (CLh - 1) : 0;
    float u_n = dt[(size_t)(base + p0i) * 256 + e];
    float x_n = xc[(size_t)(base + p0i) * 256 + e];
    for (int s = 0; s < CLh; ++s) {
        int p = dir ? (CLh - 1 - s) : s;
        float u = u_n, xv = x_n;
        if (s + 1 < CLh) {
            int p2 = dir ? (CLh - 2 - s) : (s + 1);
            u_n = dt[(size_t)(base + p2) * 256 + e];
            x_n = xc[(size_t)(base + p2) * 256 + e];
        }
        union { float4 v[4]; float f[16]; } bb, cc;
        const float4* bp = (const float4*)&bms[p][0];
        bb.v[0] = bp[0]; bb.v[1] = bp[1]; bb.v[2] = bp[2]; bb.v[3] = bp[3];
        if (PHASE == 1) {
            const float4* cp = (const float4*)&cms[p][0];
            cc.v[0] = cp[0]; cc.v[1] = cp[1]; cc.v[2] = cp[2]; cc.v[3] = cp[3];
        }
        float y = 0.f;
#pragma unroll
        for (int n = 0; n < 16; ++n) {
            float a = exp2f(A2[n] * u);
            float w = xv * bb.f[n] * iv[n];
            float t = h[n] + w;
            h[n] = a * t - w;
            if (PHASE == 1) y += h[n] * cc.f[n];
        }
        if (PHASE == 0) sdt += u;
        if (PHASE == 1) {
            float* yp = dir ? yb : yf;
            yp[(size_t)(base + p) * 256 + e] = y;
        }
    }
    if (PHASE == 0) {
#pragma unroll
        for (int j = 0; j < 4; ++j) {
            float4 hv = make_float4(h[4 * j], h[4 * j + 1], h[4 * j + 2], h[4 * j + 3]);
            *(float4*)&Hb[hofs + 4 * j] = hv;
        }
        if (dir == 0) sdtb[c * 256 + e] = sdt;
    }
}

// chunk-level scan, in place: Hb[c] <- prefix state entering chunk c
__global__ __launch_bounds__(256) void combine_k(float* __restrict__ Hb, const float* __restrict__ sdtb,
                                                 const float* __restrict__ Alog) {
    int id = blockIdx.x * 256 + threadIdx.x;   // < 8192
    int dir = id >> 12, en = id & 4095, e = en >> 4;
    float A2 = -expf(Alog[en]) * 1.44269504088896f;
    float hi = 0.f;
    for (int g = 0; g < NCh / 8; ++g) {
        float Pv[8], qv[8];
#pragma unroll
        for (int j = 0; j < 8; ++j) {
            int c = dir ? (NCh - 1 - (g * 8 + j)) : (g * 8 + j);
            Pv[j] = sdtb[c * 256 + e];
            qv[j] = Hb[(size_t)(dir * NCh + c) * 4096 + en];
        }
#pragma unroll
        for (int j = 0; j < 8; ++j) {
            int c = dir ? (NCh - 1 - (g * 8 + j)) : (g * 8 + j);
            float P = exp2f(A2 * Pv[j]);
            Hb[(size_t)(dir * NCh + c) * 4096 + en] = hi;
            hi = P * hi + qv[j];
        }
    }
}

// y = (yf + yb + D*xc) * silu(z)  -> bf16 hi/lo for Wout GEMM
__global__ __launch_bounds__(256) void gate_k(const float* __restrict__ yf, const float* __restrict__ yb,
                                              const float* __restrict__ xc, const float* __restrict__ xz,
                                              const float* __restrict__ Dp,
                                              ushort* __restrict__ yH, ushort* __restrict__ yL) {
    int i = blockIdx.x * 256 + threadIdx.x;    // < 2097152
    int e = i & 255, l = i >> 8;
    float zv = xz[(size_t)l * 512 + 256 + e];
    float yv = yf[i] + yb[i] + Dp[e] * xc[i];
    float v = yv * (zv / (1.f + expf(-zv)));
    ushort h, lo; f2hl(v, &h, &lo);
    yH[i] = h; yL[i] = lo;
}

// ---------------------------------------------------------------------------
extern "C" void kernel_launch(void* const* d_in, const int* in_sizes, int n_in,
                              void* d_out, int out_size, void* d_ws, size_t ws_size,
                              hipStream_t stream) {
    const float* ks    = (const float*)d_in[0];
    const float* mask  = (const float*)d_in[1];
    const float* pe_w  = (const float*)d_in[2];
    const float* pe_b  = (const float*)d_in[3];
    const float* pu_w  = (const float*)d_in[4];
    const float* pu_b  = (const float*)d_in[5];
    const float* ln_g  = (const float*)d_in[6];
    const float* ln_b  = (const float*)d_in[7];
    const float* fn_g  = (const float*)d_in[8];
    const float* fn_b  = (const float*)d_in[9];
    const float* cond_band = (const float*)d_in[10];
    const float* cond_rad  = (const float*)d_in[11];
    const float* cond_mask = (const float*)d_in[12];
    const float* Win   = (const float*)d_in[13];
    const float* bin_  = (const float*)d_in[14];
    const float* convw = (const float*)d_in[15];
    const float* convb = (const float*)d_in[16];
    const float* Wx    = (const float*)d_in[17];
    const float* Wdt   = (const float*)d_in[18];
    const float* bdt   = (const float*)d_in[19];
    const float* Alog  = (const float*)d_in[20];
    const float* Dp    = (const float*)d_in[21];
    const float* Wout  = (const float*)d_in[22];
    const float* bout  = (const float*)d_in[23];
    const float* edt   = (const float*)d_in[24];
    const float* eB    = (const float*)d_in[25];
    const float* eC    = (const float*)d_in[26];
    const float* wr    = (const float*)d_in[27];
    const float* wm    = (const float*)d_in[28];
    float* out = (float*)d_out;

    // workspace layout (bytes)
    char* base = (char*)d_ws;
    size_t o = 0;
    auto alloc = [&](size_t bytes) { char* p = base + o; o += (bytes + 255) & ~(size_t)255; return p; };
    float*  mbuf = (float*)alloc(32768);
    ushort* wH   = (ushort*)alloc(294912);
    ushort* wL   = (ushort*)alloc(294912);
    ushort* xinH = (ushort*)alloc(2097152);
    ushort* xinL = (ushort*)alloc(2097152);
    float*  x    = (float*)alloc(4194304);
    float*  h_   = (float*)alloc(4194304);
    ushort* hnH  = (ushort*)alloc(2097152);
    ushort* hnL  = (ushort*)alloc(2097152);
    float*  xz   = (float*)alloc(16777216);
    float*  xc   = (float*)alloc(8388608);
    ushort* xcH  = (ushort*)alloc(4194304);
    ushort* xcL  = (ushort*)alloc(4194304);
    float*  dbl  = (float*)alloc(1310720);
    float*  dt   = (float*)alloc(8388608);
    float*  Bm   = (float*)alloc(524288);
    float*  Cm   = (float*)alloc(524288);
    float*  Hb   = (float*)alloc(8388608);
    float*  sdtb = (float*)alloc(262144);
    float*  yf   = (float*)alloc(8388608);
    float*  yb   = (float*)alloc(8388608);
    ushort* yH   = (ushort*)alloc(4194304);
    ushort* yL   = (ushort*)alloc(4194304);
    ushort* hfH  = (ushort*)alloc(2097152);
    ushort* hfL  = (ushort*)alloc(2097152);

    maskpool_k<<<32, 256, 0, stream>>>(mask, mbuf);
    prep_w<<<576, 256, 0, stream>>>(pe_w, Win, Wx, Wout, pu_w, wH, wL);
    gather_k<<<4096, 256, 0, stream>>>(ks, xinH, xinL);
    // embed + cond -> x
    mgemm_k<0, 128><<<dim3(64, 2), 256, 0, stream>>>(xinH, xinL, wH, wL, x, nullptr, nullptr,
                                                     pe_b, cond_band, cond_rad, cond_mask, mbuf);
    // double LN -> h_, hn(hi/lo)
    ln2_k<<<8192, 128, 0, stream>>>(x, ln_g, ln_b, fn_g, fn_b, h_, hnH, hnL);
    // Win -> xz
    mgemm_k<1, 128><<<dim3(64, 8), 256, 0, stream>>>(hnH, hnL, wH + 16384, wL + 16384, xz, nullptr, nullptr,
                                                     bin_, nullptr, nullptr, nullptr, nullptr);
    // conv + silu -> xc (fp32 + hi/lo)
    conv_k<<<8192, 256, 0, stream>>>(xz, convw, convb, xc, xcH, xcL);
    // Wx -> dbl
    mgemm_k<4, 256><<<dim3(64, 1), 256, 0, stream>>>(xcH, xcL, wH + 81920, wL + 81920, dbl, nullptr, nullptr,
                                                     nullptr, nullptr, nullptr, nullptr, nullptr);
    // dt / Bm / Cm
    dtk_k<<<8192, 256, 0, stream>>>(dbl, Wdt, bdt, mbuf, edt, eB, eC, wr, wm, dt, Bm, Cm);
    // scan
    scan_k<0><<<dim3(NCh, 2), 256, 0, stream>>>(dt, xc, Bm, Cm, Alog, Hb, sdtb, nullptr, nullptr);
    combine_k<<<32, 256, 0, stream>>>(Hb, sdtb, Alog);
    scan_k<1><<<dim3(NCh, 2), 256, 0, stream>>>(dt, xc, Bm, Cm, Alog, Hb, sdtb, yf, yb);
    // gate -> y (hi/lo)
    gate_k<<<8192, 256, 0, stream>>>(yf, yb, xc, xz, Dp, yH, yL);
    // Wout + residual -> hf (hi/lo)
    mgemm_k<2, 256><<<dim3(64, 2), 256, 0, stream>>>(yH, yL, wH + 98304, wL + 98304, nullptr, hfH, hfL,
                                                     bout, h_, nullptr, nullptr, nullptr);
    // unembed + residual -> out
    mgemm_k<3, 128><<<dim3(64, 2), 256, 0, stream>>>(hfH, hfL, wH + 131072, wL + 131072, out, nullptr, nullptr,
                                                     pu_b, ks, nullptr, nullptr, nullptr);
}

// Round 4
// 281.345 us; speedup vs baseline: 1.4306x; 1.0498x over previous
//
#include <hip/hip_runtime.h>
#include <hip/hip_bf16.h>

#define L_TOK 8192
#define NCh 256   // scan chunks
#define CLh 32    // chunk length

typedef short bf16x8 __attribute__((ext_vector_type(8)));
typedef float f32x4 __attribute__((ext_vector_type(4)));

static __device__ __forceinline__ ushort f2bf(float x) {
    union { float f; uint u; } v; v.f = x;
    uint r = v.u + 0x7fffu + ((v.u >> 16) & 1u);
    return (ushort)(r >> 16);
}
static __device__ __forceinline__ float bf2f(ushort h) {
    union { float f; uint u; } v; v.u = ((uint)h) << 16;
    return v.f;
}
static __device__ __forceinline__ void f2hl(float x, ushort* hi, ushort* lo) {
    ushort h = f2bf(x);
    *hi = h;
    *lo = f2bf(x - bf2f(h));
}

// weight regions in wH/wL (ushort elems), all K-major [n][k]:
//   pe    @ 0      : n=128,k=128
//   Win^T @ 16384  : n=512,k=128
//   Wout^T@ 81920  : n=128,k=256
//   pu^T  @ 114688 : n=128,k=128
//   proj  @ 131072 : n=320,k=256  (n<256: Wx[:,:8]@Wdt fused; 256..287: Wx B/C cols; rest 0)
#define W_PE   0
#define W_WIN  16384
#define W_WOUT 81920
#define W_PU   114688
#define W_PROJ 131072
#define W_TOT  212992

// ---------------------------------------------------------------------------
// prep: weights -> bf16 hi/lo (with transposes + Wx@Wdt fusion) ; maskpool
__global__ __launch_bounds__(256) void prep_k(const float* __restrict__ pe_w, const float* __restrict__ Win,
                                              const float* __restrict__ Wx, const float* __restrict__ Wdt,
                                              const float* __restrict__ Wout, const float* __restrict__ pu_w,
                                              const float* __restrict__ mask,
                                              ushort* __restrict__ wH, ushort* __restrict__ wL,
                                              float* __restrict__ mbuf) {
    int b = blockIdx.x;
    if (b >= 832) {  // maskpool
        int l = (b - 832) * 256 + threadIdx.x;
        int xg = l >> 8, yg = (l >> 3) & 31, zg = l & 7;
        float s = 0.f;
        for (int i2 = 0; i2 < 2; ++i2)
            for (int j2 = 0; j2 < 2; ++j2)
                for (int k2 = 0; k2 < 2; ++k2)
                    s += mask[(2 * xg + i2) * 1024 + (2 * yg + j2) * 16 + 2 * zg + k2];
        s *= 0.125f;
        mbuf[l] = fminf(fmaxf(s, 0.f), 1.f);
        return;
    }
    int i = b * 256 + threadIdx.x;  // < 212992
    float v;
    if (i < 16384) {
        v = pe_w[i];
    } else if (i < 81920) {
        int j = i - 16384; int n = j >> 7, k = j & 127;
        v = Win[k * 512 + n];
    } else if (i < 114688) {
        int j = i - 81920; int n = j >> 8, k = j & 255;
        v = Wout[k * 128 + n];
    } else if (i < 131072) {
        int j = i - 114688; int n = j >> 7, k = j & 127;
        v = pu_w[k * 128 + n];
    } else {
        int j = i - 131072; int n = j >> 8, k = j & 255;
        if (n < 256) {
            float s = 0.f;
#pragma unroll
            for (int r = 0; r < 8; ++r) s += Wx[k * 40 + r] * Wdt[r * 256 + n];
            v = s;
        } else if (n < 288) {
            v = Wx[k * 40 + 8 + (n - 256)];
        } else {
            v = 0.f;
        }
    }
    ushort h, lo; f2hl(v, &h, &lo);
    wH[i] = h; wL[i] = lo;
}

// ---------------------------------------------------------------------------
// fused: gather patches -> embed GEMM (+pe_b +cond) -> LN -> h_ ; LN2 -> hn hi/lo
// tile 32 x 128 (full N), 256 threads = 4 waves, wave w: cols w*32..+31.
__global__ __launch_bounds__(256) void embed_ln_k(const float* __restrict__ ks,
                                                  const ushort* __restrict__ wH, const ushort* __restrict__ wL,
                                                  const float* __restrict__ pe_b, const float* __restrict__ cond_band,
                                                  const float* __restrict__ cond_rad, const float* __restrict__ cond_mask,
                                                  const float* __restrict__ mbuf,
                                                  const float* __restrict__ ln_g, const float* __restrict__ ln_b,
                                                  const float* __restrict__ fn_g, const float* __restrict__ fn_b,
                                                  float* __restrict__ h_,
                                                  ushort* __restrict__ hnH, ushort* __restrict__ hnL) {
    __shared__ __align__(16) char smem[46080];
    ushort (*AsH)[72] = (ushort(*)[72])(smem);
    ushort (*AsL)[72] = (ushort(*)[72])(smem + 4608);
    ushort (*BsH)[72] = (ushort(*)[72])(smem + 9216);
    ushort (*BsL)[72] = (ushort(*)[72])(smem + 27648);
    float  (*Cs)[132] = (float(*)[132])(smem);

    const int tid = threadIdx.x;
    const int lane = tid & 63, wn = tid >> 6;
    const int ln = lane & 15, q = lane >> 4;
    const int mb = blockIdx.x * 32;

    f32x4 acc[2][2];
#pragma unroll
    for (int rb = 0; rb < 2; ++rb)
#pragma unroll
        for (int cb = 0; cb < 2; ++cb) acc[rb][cb] = (f32x4){0.f, 0.f, 0.f, 0.f};

    for (int kc = 0; kc < 128; kc += 64) {
        __syncthreads();
        // A: gather 32 x 64 from kspace
        for (int u = tid; u < 2048; u += 256) {
            int r = u >> 6, kk = u & 63;
            int l = mb + r, k = kc + kk;
            int cc = k >> 3, ijk = k & 7;
            int xg = l >> 8, yg = (l >> 3) & 31, zg = l & 7;
            int i2 = (ijk >> 2) & 1, j2 = (ijk >> 1) & 1, k2 = ijk & 1;
            float v = ks[cc * 65536 + (2 * xg + i2) * 1024 + (2 * yg + j2) * 16 + 2 * zg + k2];
            ushort h, lo; f2hl(v, &h, &lo);
            AsH[r][kk] = h; AsL[r][kk] = lo;
        }
        // B: pe 128 x 64
        for (int u = tid; u < 1024; u += 256) {
            int n = u >> 3, g = u & 7;
            *(uint4*)&BsH[n][g * 8] = *(const uint4*)&wH[W_PE + n * 128 + kc + g * 8];
            *(uint4*)&BsL[n][g * 8] = *(const uint4*)&wL[W_PE + n * 128 + kc + g * 8];
        }
        __syncthreads();
#pragma unroll
        for (int ks_ = 0; ks_ < 64; ks_ += 32) {
            const int kk = ks_ + q * 8;
            bf16x8 ah[2], al[2], bh[2], bl[2];
#pragma unroll
            for (int rb = 0; rb < 2; ++rb) {
                ah[rb] = *(const bf16x8*)&AsH[rb * 16 + ln][kk];
                al[rb] = *(const bf16x8*)&AsL[rb * 16 + ln][kk];
            }
#pragma unroll
            for (int cb = 0; cb < 2; ++cb) {
                bh[cb] = *(const bf16x8*)&BsH[wn * 32 + cb * 16 + ln][kk];
                bl[cb] = *(const bf16x8*)&BsL[wn * 32 + cb * 16 + ln][kk];
            }
#pragma unroll
            for (int rb = 0; rb < 2; ++rb)
#pragma unroll
                for (int cb = 0; cb < 2; ++cb) {
                    acc[rb][cb] = __builtin_amdgcn_mfma_f32_16x16x32_bf16(ah[rb], bh[cb], acc[rb][cb], 0, 0, 0);
                    acc[rb][cb] = __builtin_amdgcn_mfma_f32_16x16x32_bf16(ah[rb], bl[cb], acc[rb][cb], 0, 0, 0);
                    acc[rb][cb] = __builtin_amdgcn_mfma_f32_16x16x32_bf16(al[rb], bh[cb], acc[rb][cb], 0, 0, 0);
                }
        }
    }
    __syncthreads();
    // epilogue: + pe_b + cond -> Cs (LDS reused)
#pragma unroll
    for (int rb = 0; rb < 2; ++rb) {
#pragma unroll
        for (int cb = 0; cb < 2; ++cb) {
#pragma unroll
            for (int r = 0; r < 4; ++r) {
                int row = rb * 16 + q * 4 + r;
                int col = wn * 32 + cb * 16 + ln;
                int l = mb + row;
                float rho = (float)l * (1.0f / 8191.0f);
                int band = min(7, (int)(rho * 8.0f));
                Cs[row][col] = acc[rb][cb][r] + pe_b[col] + cond_band[band * 128 + col]
                               + rho * cond_rad[col] + mbuf[l] * cond_mask[col];
            }
        }
    }
    __syncthreads();
    // LN: 32 rows x 8 threads, 16 cols each
    {
        int row = tid >> 3, j = tid & 7;
        int l = mb + row;
        float v16[16];
        float s = 0.f, s2 = 0.f;
#pragma unroll
        for (int i = 0; i < 16; ++i) {
            float v = Cs[row][j * 16 + i];
            v16[i] = v; s += v; s2 += v * v;
        }
#pragma unroll
        for (int o = 1; o < 8; o <<= 1) { s += __shfl_xor(s, o, 8); s2 += __shfl_xor(s2, o, 8); }
        float mu = s * (1.f / 128.f);
        float var = s2 * (1.f / 128.f) - mu * mu;
        float rstd = rsqrtf(fmaxf(var, 0.f) + 1e-5f);
        float hv[16];
        s = 0.f; s2 = 0.f;
#pragma unroll
        for (int i = 0; i < 16; ++i) {
            int col = j * 16 + i;
            float h = (v16[i] - mu) * rstd * ln_g[col] + ln_b[col];
            hv[i] = h; s += h; s2 += h * h;
        }
        // write h_
#pragma unroll
        for (int i = 0; i < 16; i += 4)
            *(float4*)&h_[(size_t)l * 128 + j * 16 + i] = make_float4(hv[i], hv[i + 1], hv[i + 2], hv[i + 3]);
#pragma unroll
        for (int o = 1; o < 8; o <<= 1) { s += __shfl_xor(s, o, 8); s2 += __shfl_xor(s2, o, 8); }
        mu = s * (1.f / 128.f);
        var = s2 * (1.f / 128.f) - mu * mu;
        rstd = rsqrtf(fmaxf(var, 0.f) + 1e-5f);
        union { ushort u[16]; uint4 v4[2]; } oh, ol;
#pragma unroll
        for (int i = 0; i < 16; ++i) {
            int col = j * 16 + i;
            float o2 = (hv[i] - mu) * rstd * fn_g[col] + fn_b[col];
            ushort hh, ll; f2hl(o2, &hh, &ll);
            oh.u[i] = hh; ol.u[i] = ll;
        }
        *(uint4*)&hnH[(size_t)l * 128 + j * 16] = oh.v4[0];
        *(uint4*)&hnH[(size_t)l * 128 + j * 16 + 8] = oh.v4[1];
        *(uint4*)&hnL[(size_t)l * 128 + j * 16] = ol.v4[0];
        *(uint4*)&hnL[(size_t)l * 128 + j * 16 + 8] = ol.v4[1];
    }
}

// ---------------------------------------------------------------------------
// Win GEMM: xz = hn @ Win + bin ; xp (cols<256) raw, sz (cols>=256) = silu
// tile 128x64, waves 2x2 (wave: 64x32)
__global__ __launch_bounds__(256) void win_k(const ushort* __restrict__ Ah, const ushort* __restrict__ Al,
                                             const ushort* __restrict__ wH, const ushort* __restrict__ wL,
                                             const float* __restrict__ bin_,
                                             float* __restrict__ xp, float* __restrict__ sz) {
    __shared__ ushort AsH[128][72], AsL[128][72];
    __shared__ ushort BsH[64][72], BsL[64][72];
    const int tid = threadIdx.x;
    const int lane = tid & 63, wave = tid >> 6;
    const int wm = wave & 1, wn = wave >> 1;
    const int ln = lane & 15, q = lane >> 4;
    const int mb = blockIdx.x * 128, nb = blockIdx.y * 64;

    f32x4 acc[4][2];
#pragma unroll
    for (int rb = 0; rb < 4; ++rb)
#pragma unroll
        for (int cb = 0; cb < 2; ++cb) acc[rb][cb] = (f32x4){0.f, 0.f, 0.f, 0.f};

    for (int kc = 0; kc < 128; kc += 64) {
        __syncthreads();
        for (int u = tid; u < 1024; u += 256) {
            int r = u >> 3, g = u & 7;
            size_t go = (size_t)(mb + r) * 128 + kc + g * 8;
            *(uint4*)&AsH[r][g * 8] = *(const uint4*)&Ah[go];
            *(uint4*)&AsL[r][g * 8] = *(const uint4*)&Al[go];
        }
        for (int u = tid; u < 512; u += 256) {
            int n = u >> 3, g = u & 7;
            size_t go = (size_t)(W_WIN) + (size_t)(nb + n) * 128 + kc + g * 8;
            *(uint4*)&BsH[n][g * 8] = *(const uint4*)&wH[go];
            *(uint4*)&BsL[n][g * 8] = *(const uint4*)&wL[go];
        }
        __syncthreads();
#pragma unroll
        for (int ks_ = 0; ks_ < 64; ks_ += 32) {
            const int kk = ks_ + q * 8;
            bf16x8 ah[4], al[4], bh[2], bl[2];
#pragma unroll
            for (int rb = 0; rb < 4; ++rb) {
                ah[rb] = *(const bf16x8*)&AsH[wm * 64 + rb * 16 + ln][kk];
                al[rb] = *(const bf16x8*)&AsL[wm * 64 + rb * 16 + ln][kk];
            }
#pragma unroll
            for (int cb = 0; cb < 2; ++cb) {
                bh[cb] = *(const bf16x8*)&BsH[wn * 32 + cb * 16 + ln][kk];
                bl[cb] = *(const bf16x8*)&BsL[wn * 32 + cb * 16 + ln][kk];
            }
#pragma unroll
            for (int rb = 0; rb < 4; ++rb)
#pragma unroll
                for (int cb = 0; cb < 2; ++cb) {
                    acc[rb][cb] = __builtin_amdgcn_mfma_f32_16x16x32_bf16(ah[rb], bh[cb], acc[rb][cb], 0, 0, 0);
                    acc[rb][cb] = __builtin_amdgcn_mfma_f32_16x16x32_bf16(ah[rb], bl[cb], acc[rb][cb], 0, 0, 0);
                    acc[rb][cb] = __builtin_amdgcn_mfma_f32_16x16x32_bf16(al[rb], bh[cb], acc[rb][cb], 0, 0, 0);
                }
        }
    }
#pragma unroll
    for (int rb = 0; rb < 4; ++rb)
#pragma unroll
        for (int cb = 0; cb < 2; ++cb)
#pragma unroll
            for (int r = 0; r < 4; ++r) {
                int l = mb + wm * 64 + rb * 16 + q * 4 + r;
                int col = nb + wn * 32 + cb * 16 + ln;
                float v = acc[rb][cb][r] + bin_[col];
                if (col < 256) {
                    xp[(size_t)l * 256 + col] = v;
                } else {
                    sz[(size_t)l * 256 + (col - 256)] = v / (1.f + expf(-v));
                }
            }
}

// causal depthwise conv (4 taps) + SiLU, float4 over channels
__global__ __launch_bounds__(256) void conv_k(const float* __restrict__ xp, const float* __restrict__ convw,
                                              const float* __restrict__ convb, float* __restrict__ xc) {
    int id = blockIdx.x * 256 + threadIdx.x;   // < 524288
    int l = id >> 6, e4 = (id & 63) * 4;
    float4 cw[4];
#pragma unroll
    for (int j = 0; j < 4; ++j) cw[j] = *(const float4*)&convw[(e4 + j) * 4];
    float4 cb = *(const float4*)&convb[e4];
    float o[4] = {cb.x, cb.y, cb.z, cb.w};
#pragma unroll
    for (int k = 0; k < 4; ++k) {
        int lp = l - 3 + k;
        if (lp >= 0) {
            float4 t = *(const float4*)&xp[(size_t)lp * 256 + e4];
            o[0] += t.x * ((const float*)&cw[0])[k];
            o[1] += t.y * ((const float*)&cw[1])[k];
            o[2] += t.z * ((const float*)&cw[2])[k];
            o[3] += t.w * ((const float*)&cw[3])[k];
        }
    }
    float4 r;
    r.x = o[0] / (1.f + expf(-o[0]));
    r.y = o[1] / (1.f + expf(-o[1]));
    r.z = o[2] / (1.f + expf(-o[2]));
    r.w = o[3] / (1.f + expf(-o[3]));
    *(float4*)&xc[(size_t)l * 256 + e4] = r;
}

// ---------------------------------------------------------------------------
// proj GEMM: xc @ [Wfused | WxBC] (N=288, padded 320); epilogue -> dt / Bm / Cm
// tile 128x64, A = xc fp32 converted inline
__global__ __launch_bounds__(256) void proj_k(const float* __restrict__ xc,
                                              const ushort* __restrict__ wH, const ushort* __restrict__ wL,
                                              const float* __restrict__ bdt, const float* __restrict__ mbuf,
                                              const float* __restrict__ edt, const float* __restrict__ eB,
                                              const float* __restrict__ eC, const float* __restrict__ wr,
                                              const float* __restrict__ wm,
                                              float* __restrict__ dt, float* __restrict__ Bm, float* __restrict__ Cm) {
    __shared__ ushort AsH[128][72], AsL[128][72];
    __shared__ ushort BsH[64][72], BsL[64][72];
    const int tid = threadIdx.x;
    const int lane = tid & 63, wave = tid >> 6;
    const int wm_ = wave & 1, wn = wave >> 1;
    const int ln = lane & 15, q = lane >> 4;
    const int mb = blockIdx.x * 128, nb = blockIdx.y * 64;

    f32x4 acc[4][2];
#pragma unroll
    for (int rb = 0; rb < 4; ++rb)
#pragma unroll
        for (int cb = 0; cb < 2; ++cb) acc[rb][cb] = (f32x4){0.f, 0.f, 0.f, 0.f};

    for (int kc = 0; kc < 256; kc += 64) {
        __syncthreads();
        for (int u = tid; u < 2048; u += 256) {
            int r = u >> 4, kq = u & 15;
            float4 v = *(const float4*)&xc[(size_t)(mb + r) * 256 + kc + kq * 4];
            union { ushort u[4]; uint2 v2; } hh, ll;
            f2hl(v.x, &hh.u[0], &ll.u[0]); f2hl(v.y, &hh.u[1], &ll.u[1]);
            f2hl(v.z, &hh.u[2], &ll.u[2]); f2hl(v.w, &hh.u[3], &ll.u[3]);
            *(uint2*)&AsH[r][kq * 4] = hh.v2;
            *(uint2*)&AsL[r][kq * 4] = ll.v2;
        }
        for (int u = tid; u < 512; u += 256) {
            int n = u >> 3, g = u & 7;
            size_t go = (size_t)(W_PROJ) + (size_t)(nb + n) * 256 + kc + g * 8;
            *(uint4*)&BsH[n][g * 8] = *(const uint4*)&wH[go];
            *(uint4*)&BsL[n][g * 8] = *(const uint4*)&wL[go];
        }
        __syncthreads();
#pragma unroll
        for (int ks_ = 0; ks_ < 64; ks_ += 32) {
            const int kk = ks_ + q * 8;
            bf16x8 ah[4], al[4], bh[2], bl[2];
#pragma unroll
            for (int rb = 0; rb < 4; ++rb) {
                ah[rb] = *(const bf16x8*)&AsH[wm_ * 64 + rb * 16 + ln][kk];
                al[rb] = *(const bf16x8*)&AsL[wm_ * 64 + rb * 16 + ln][kk];
            }
#pragma unroll
            for (int cb = 0; cb < 2; ++cb) {
                bh[cb] = *(const bf16x8*)&BsH[wn * 32 + cb * 16 + ln][kk];
                bl[cb] = *(const bf16x8*)&BsL[wn * 32 + cb * 16 + ln][kk];
            }
#pragma unroll
            for (int rb = 0; rb < 4; ++rb)
#pragma unroll
                for (int cb = 0; cb < 2; ++cb) {
                    acc[rb][cb] = __builtin_amdgcn_mfma_f32_16x16x32_bf16(ah[rb], bh[cb], acc[rb][cb], 0, 0, 0);
                    acc[rb][cb] = __builtin_amdgcn_mfma_f32_16x16x32_bf16(ah[rb], bl[cb], acc[rb][cb], 0, 0, 0);
                    acc[rb][cb] = __builtin_amdgcn_mfma_f32_16x16x32_bf16(al[rb], bh[cb], acc[rb][cb], 0, 0, 0);
                }
        }
    }
#pragma unroll
    for (int rb = 0; rb < 4; ++rb)
#pragma unroll
        for (int cb = 0; cb < 2; ++cb)
#pragma unroll
            for (int r = 0; r < 4; ++r) {
                int l = mb + wm_ * 64 + rb * 16 + q * 4 + r;
                int col = nb + wn * 32 + cb * 16 + ln;
                float v = acc[rb][cb][r];
                float rho = (float)l * (1.0f / 8191.0f);
                int band = min(7, (int)(rho * 8.0f));
                float mv = mbuf[l];
                if (col < 256) {
                    float sc0 = 2.0f / (1.f + expf(-(edt[band] + wr[0] * rho + wm[0] * mv)));
                    float v2 = v + bdt[col];
                    float sp = (v2 > 20.f) ? v2 : log1pf(expf(v2));
                    dt[(size_t)l * 256 + col] = sp * sc0;
                } else if (col < 272) {
                    float sc1 = 2.0f / (1.f + expf(-(eB[band] + wr[1] * rho + wm[1] * mv)));
                    Bm[(size_t)l * 16 + (col - 256)] = v * sc1;
                } else if (col < 288) {
                    float sc2 = 2.0f / (1.f + expf(-(eC[band] + wr[2] * rho + wm[2] * mv)));
                    Cm[(size_t)l * 16 + (col - 272)] = v * sc2;
                }
            }
}

// ---------------------------------------------------------------------------
// scan, one lane per channel e, h[16] in registers.
template <int PHASE>
__global__ __launch_bounds__(256) void scan_k(const float* __restrict__ dt, const float* __restrict__ xc,
                                              const float* __restrict__ Bm, const float* __restrict__ Cm,
                                              const float* __restrict__ Alog,
                                              float* __restrict__ Hb, float* __restrict__ sdtb,
                                              float* __restrict__ yf, float* __restrict__ yb) {
    const int c = blockIdx.x, dir = blockIdx.y, e = threadIdx.x;
    __shared__ float bms[CLh][16];
    __shared__ float cms[CLh][16];
    for (int idx = e; idx < CLh * 16; idx += 256) {
        bms[idx >> 4][idx & 15] = Bm[c * (CLh * 16) + idx];
        if (PHASE == 1) cms[idx >> 4][idx & 15] = Cm[c * (CLh * 16) + idx];
    }
    float A2[16], iv[16], h[16];
#pragma unroll
    for (int n = 0; n < 16; ++n) {
        float ea = expf(Alog[e * 16 + n]);
        A2[n] = -ea * 1.44269504088896f;
        iv[n] = -1.0f / ea;
    }
    const size_t hofs = (size_t)(dir * NCh + c) * 4096 + e * 16;
    if (PHASE == 0) {
#pragma unroll
        for (int n = 0; n < 16; ++n) h[n] = 0.f;
    } else {
#pragma unroll
        for (int j = 0; j < 4; ++j) {
            float4 hv = *(const float4*)&Hb[hofs + 4 * j];
            h[4 * j] = hv.x; h[4 * j + 1] = hv.y; h[4 * j + 2] = hv.z; h[4 * j + 3] = hv.w;
        }
    }
    __syncthreads();
    const int base = c * CLh;
    float sdt = 0.f;
    int p0i = dir ? (CLh - 1) : 0;
    float u_n = dt[(size_t)(base + p0i) * 256 + e];
    float x_n = xc[(size_t)(base + p0i) * 256 + e];
    for (int s = 0; s < CLh; ++s) {
        int p = dir ? (CLh - 1 - s) : s;
        float u = u_n, xv = x_n;
        if (s + 1 < CLh) {
            int p2 = dir ? (CLh - 2 - s) : (s + 1);
            u_n = dt[(size_t)(base + p2) * 256 + e];
            x_n = xc[(size_t)(base + p2) * 256 + e];
        }
        union { float4 v[4]; float f[16]; } bb, cc;
        const float4* bp = (const float4*)&bms[p][0];
        bb.v[0] = bp[0]; bb.v[1] = bp[1]; bb.v[2] = bp[2]; bb.v[3] = bp[3];
        if (PHASE == 1) {
            const float4* cp = (const float4*)&cms[p][0];
            cc.v[0] = cp[0]; cc.v[1] = cp[1]; cc.v[2] = cp[2]; cc.v[3] = cp[3];
        }
        float y = 0.f;
#pragma unroll
        for (int n = 0; n < 16; ++n) {
            float a = exp2f(A2[n] * u);
            float w = xv * bb.f[n] * iv[n];
            float t = h[n] + w;
            h[n] = a * t - w;
            if (PHASE == 1) y += h[n] * cc.f[n];
        }
        if (PHASE == 0) sdt += u;
        if (PHASE == 1) {
            float* yp = dir ? yb : yf;
            yp[(size_t)(base + p) * 256 + e] = y;
        }
    }
    if (PHASE == 0) {
#pragma unroll
        for (int j = 0; j < 4; ++j) {
            float4 hv = make_float4(h[4 * j], h[4 * j + 1], h[4 * j + 2], h[4 * j + 3]);
            *(float4*)&Hb[hofs + 4 * j] = hv;
        }
        if (dir == 0) sdtb[c * 256 + e] = sdt;
    }
}

// chunk-level scan, in place: Hb[c] <- prefix state entering chunk c
__global__ __launch_bounds__(256) void combine_k(float* __restrict__ Hb, const float* __restrict__ sdtb,
                                                 const float* __restrict__ Alog) {
    int id = blockIdx.x * 256 + threadIdx.x;   // < 8192
    int dir = id >> 12, en = id & 4095, e = en >> 4;
    float A2 = -expf(Alog[en]) * 1.44269504088896f;
    float hi = 0.f;
    for (int g = 0; g < NCh / 8; ++g) {
        float Pv[8], qv[8];
#pragma unroll
        for (int j = 0; j < 8; ++j) {
            int c = dir ? (NCh - 1 - (g * 8 + j)) : (g * 8 + j);
            Pv[j] = sdtb[c * 256 + e];
            qv[j] = Hb[(size_t)(dir * NCh + c) * 4096 + en];
        }
#pragma unroll
        for (int j = 0; j < 8; ++j) {
            int c = dir ? (NCh - 1 - (g * 8 + j)) : (g * 8 + j);
            float P = exp2f(A2 * Pv[j]);
            Hb[(size_t)(dir * NCh + c) * 4096 + en] = hi;
            hi = P * hi + qv[j];
        }
    }
}

// ---------------------------------------------------------------------------
// Wout GEMM with gate fused in A-staging: A = (yf+yb+D*xc)*sz -> hi/lo
// tile 64x64 (waves 2x2, wave 32x32), grid (128,2); epilogue +bout +h_ -> hf hi/lo
__global__ __launch_bounds__(256) void wout_k(const float* __restrict__ yf, const float* __restrict__ yb,
                                              const float* __restrict__ xc, const float* __restrict__ sz,
                                              const float* __restrict__ Dp,
                                              const ushort* __restrict__ wH, const ushort* __restrict__ wL,
                                              const float* __restrict__ bout, const float* __restrict__ h_,
                                              ushort* __restrict__ hfH, ushort* __restrict__ hfL) {
    __shared__ ushort AsH[64][72], AsL[64][72];
    __shared__ ushort BsH[64][72], BsL[64][72];
    const int tid = threadIdx.x;
    const int lane = tid & 63, wave = tid >> 6;
    const int wm = wave & 1, wn = wave >> 1;
    const int ln = lane & 15, q = lane >> 4;
    const int mb = blockIdx.x * 64, nb = blockIdx.y * 64;

    f32x4 acc[2][2];
#pragma unroll
    for (int rb = 0; rb < 2; ++rb)
#pragma unroll
        for (int cb = 0; cb < 2; ++cb) acc[rb][cb] = (f32x4){0.f, 0.f, 0.f, 0.f};

    for (int kc = 0; kc < 256; kc += 64) {
        __syncthreads();
        for (int u = tid; u < 1024; u += 256) {
            int r = u >> 4, kq = u & 15;
            size_t go = (size_t)(mb + r) * 256 + kc + kq * 4;
            float4 a = *(const float4*)&yf[go];
            float4 b = *(const float4*)&yb[go];
            float4 x = *(const float4*)&xc[go];
            float4 s = *(const float4*)&sz[go];
            float4 d = *(const float4*)&Dp[kc + kq * 4];
            float v0 = (a.x + b.x + d.x * x.x) * s.x;
            float v1 = (a.y + b.y + d.y * x.y) * s.y;
            float v2 = (a.z + b.z + d.z * x.z) * s.z;
            float v3 = (a.w + b.w + d.w * x.w) * s.w;
            union { ushort u[4]; uint2 v2; } hh, ll;
            f2hl(v0, &hh.u[0], &ll.u[0]); f2hl(v1, &hh.u[1], &ll.u[1]);
            f2hl(v2, &hh.u[2], &ll.u[2]); f2hl(v3, &hh.u[3], &ll.u[3]);
            *(uint2*)&AsH[r][kq * 4] = hh.v2;
            *(uint2*)&AsL[r][kq * 4] = ll.v2;
        }
        for (int u = tid; u < 512; u += 256) {
            int n = u >> 3, g = u & 7;
            size_t go = (size_t)(W_WOUT) + (size_t)(nb + n) * 256 + kc + g * 8;
            *(uint4*)&BsH[n][g * 8] = *(const uint4*)&wH[go];
            *(uint4*)&BsL[n][g * 8] = *(const uint4*)&wL[go];
        }
        __syncthreads();
#pragma unroll
        for (int ks_ = 0; ks_ < 64; ks_ += 32) {
            const int kk = ks_ + q * 8;
            bf16x8 ah[2], al[2], bh[2], bl[2];
#pragma unroll
            for (int rb = 0; rb < 2; ++rb) {
                ah[rb] = *(const bf16x8*)&AsH[wm * 32 + rb * 16 + ln][kk];
                al[rb] = *(const bf16x8*)&AsL[wm * 32 + rb * 16 + ln][kk];
            }
#pragma unroll
            for (int cb = 0; cb < 2; ++cb) {
                bh[cb] = *(const bf16x8*)&BsH[wn * 32 + cb * 16 + ln][kk];
                bl[cb] = *(const bf16x8*)&BsL[wn * 32 + cb * 16 + ln][kk];
            }
#pragma unroll
            for (int rb = 0; rb < 2; ++rb)
#pragma unroll
                for (int cb = 0; cb < 2; ++cb) {
                    acc[rb][cb] = __builtin_amdgcn_mfma_f32_16x16x32_bf16(ah[rb], bh[cb], acc[rb][cb], 0, 0, 0);
                    acc[rb][cb] = __builtin_amdgcn_mfma_f32_16x16x32_bf16(ah[rb], bl[cb], acc[rb][cb], 0, 0, 0);
                    acc[rb][cb] = __builtin_amdgcn_mfma_f32_16x16x32_bf16(al[rb], bh[cb], acc[rb][cb], 0, 0, 0);
                }
        }
    }
#pragma unroll
    for (int rb = 0; rb < 2; ++rb)
#pragma unroll
        for (int cb = 0; cb < 2; ++cb)
#pragma unroll
            for (int r = 0; r < 4; ++r) {
                int l = mb + wm * 32 + rb * 16 + q * 4 + r;
                int col = nb + wn * 32 + cb * 16 + ln;
                float v = acc[rb][cb][r] + bout[col] + h_[(size_t)l * 128 + col];
                ushort hh, ll; f2hl(v, &hh, &ll);
                hfH[(size_t)l * 128 + col] = hh;
                hfL[(size_t)l * 128 + col] = ll;
            }
}

// unembed GEMM: out = hf @ pu^T + pu_b + ks (scattered); tile 64x64, grid (128,2)
__global__ __launch_bounds__(256) void unembed_k(const ushort* __restrict__ Ah, const ushort* __restrict__ Al,
                                                 const ushort* __restrict__ wH, const ushort* __restrict__ wL,
                                                 const float* __restrict__ pu_b, const float* __restrict__ ks,
                                                 float* __restrict__ out) {
    __shared__ ushort AsH[64][72], AsL[64][72];
    __shared__ ushort BsH[64][72], BsL[64][72];
    const int tid = threadIdx.x;
    const int lane = tid & 63, wave = tid >> 6;
    const int wm = wave & 1, wn = wave >> 1;
    const int ln = lane & 15, q = lane >> 4;
    const int mb = blockIdx.x * 64, nb = blockIdx.y * 64;

    f32x4 acc[2][2];
#pragma unroll
    for (int rb = 0; rb < 2; ++rb)
#pragma unroll
        for (int cb = 0; cb < 2; ++cb) acc[rb][cb] = (f32x4){0.f, 0.f, 0.f, 0.f};

    for (int kc = 0; kc < 128; kc += 64) {
        __syncthreads();
        for (int u = tid; u < 512; u += 256) {
            int r = u >> 3, g = u & 7;
            size_t go = (size_t)(mb + r) * 128 + kc + g * 8;
            *(uint4*)&AsH[r][g * 8] = *(const uint4*)&Ah[go];
            *(uint4*)&AsL[r][g * 8] = *(const uint4*)&Al[go];
        }
        for (int u = tid; u < 512; u += 256) {
            int n = u >> 3, g = u & 7;
            size_t go = (size_t)(W_PU) + (size_t)(nb + n) * 128 + kc + g * 8;
            *(uint4*)&BsH[n][g * 8] = *(const uint4*)&wH[go];
            *(uint4*)&BsL[n][g * 8] = *(const uint4*)&wL[go];
        }
        __syncthreads();
#pragma unroll
        for (int ks_ = 0; ks_ < 64; ks_ += 32) {
            const int kk = ks_ + q * 8;
            bf16x8 ah[2], al[2], bh[2], bl[2];
#pragma unroll
            for (int rb = 0; rb < 2; ++rb) {
                ah[rb] = *(const bf16x8*)&AsH[wm * 32 + rb * 16 + ln][kk];
                al[rb] = *(const bf16x8*)&AsL[wm * 32 + rb * 16 + ln][kk];
            }
#pragma unroll
            for (int cb = 0; cb < 2; ++cb) {
                bh[cb] = *(const bf16x8*)&BsH[wn * 32 + cb * 16 + ln][kk];
                bl[cb] = *(const bf16x8*)&BsL[wn * 32 + cb * 16 + ln][kk];
            }
#pragma unroll
            for (int rb = 0; rb < 2; ++rb)
#pragma unroll
                for (int cb = 0; cb < 2; ++cb) {
                    acc[rb][cb] = __builtin_amdgcn_mfma_f32_16x16x32_bf16(ah[rb], bh[cb], acc[rb][cb], 0, 0, 0);
                    acc[rb][cb] = __builtin_amdgcn_mfma_f32_16x16x32_bf16(ah[rb], bl[cb], acc[rb][cb], 0, 0, 0);
                    acc[rb][cb] = __builtin_amdgcn_mfma_f32_16x16x32_bf16(al[rb], bh[cb], acc[rb][cb], 0, 0, 0);
                }
        }
    }
#pragma unroll
    for (int rb = 0; rb < 2; ++rb)
#pragma unroll
        for (int cb = 0; cb < 2; ++cb)
#pragma unroll
            for (int r = 0; r < 4; ++r) {
                int l = mb + wm * 32 + rb * 16 + q * 4 + r;
                int col = nb + wn * 32 + cb * 16 + ln;
                int xg = l >> 8, yg = (l >> 3) & 31, zg = l & 7;
                int c = col >> 3, ijk = col & 7;
                int i2 = (ijk >> 2) & 1, j2 = (ijk >> 1) & 1, k2 = ijk & 1;
                size_t idx = (size_t)((c * 64 + 2 * xg + i2) * 64 + (2 * yg + j2)) * 16 + 2 * zg + k2;
                out[idx] = acc[rb][cb][r] + pu_b[c] + ks[idx];
            }
}

// ---------------------------------------------------------------------------
extern "C" void kernel_launch(void* const* d_in, const int* in_sizes, int n_in,
                              void* d_out, int out_size, void* d_ws, size_t ws_size,
                              hipStream_t stream) {
    const float* ks    = (const float*)d_in[0];
    const float* mask  = (const float*)d_in[1];
    const float* pe_w  = (const float*)d_in[2];
    const float* pe_b  = (const float*)d_in[3];
    const float* pu_w  = (const float*)d_in[4];
    const float* pu_b  = (const float*)d_in[5];
    const float* ln_g  = (const float*)d_in[6];
    const float* ln_b  = (const float*)d_in[7];
    const float* fn_g  = (const float*)d_in[8];
    const float* fn_b  = (const float*)d_in[9];
    const float* cond_band = (const float*)d_in[10];
    const float* cond_rad  = (const float*)d_in[11];
    const float* cond_mask = (const float*)d_in[12];
    const float* Win   = (const float*)d_in[13];
    const float* bin_  = (const float*)d_in[14];
    const float* convw = (const float*)d_in[15];
    const float* convb = (const float*)d_in[16];
    const float* Wx    = (const float*)d_in[17];
    const float* Wdt   = (const float*)d_in[18];
    const float* bdt   = (const float*)d_in[19];
    const float* Alog  = (const float*)d_in[20];
    const float* Dp    = (const float*)d_in[21];
    const float* Wout  = (const float*)d_in[22];
    const float* bout  = (const float*)d_in[23];
    const float* edt   = (const float*)d_in[24];
    const float* eB    = (const float*)d_in[25];
    const float* eC    = (const float*)d_in[26];
    const float* wr    = (const float*)d_in[27];
    const float* wm    = (const float*)d_in[28];
    float* out = (float*)d_out;

    char* base = (char*)d_ws;
    size_t o = 0;
    auto alloc = [&](size_t bytes) { char* p = base + o; o += (bytes + 255) & ~(size_t)255; return p; };
    float*  mbuf = (float*)alloc(32768);
    ushort* wH   = (ushort*)alloc(W_TOT * 2);
    ushort* wL   = (ushort*)alloc(W_TOT * 2);
    float*  h_   = (float*)alloc(4194304);
    ushort* hnH  = (ushort*)alloc(2097152);
    ushort* hnL  = (ushort*)alloc(2097152);
    float*  xp   = (float*)alloc(8388608);
    float*  sz   = (float*)alloc(8388608);
    float*  xc   = (float*)alloc(8388608);
    float*  dt   = (float*)alloc(8388608);
    float*  Bm   = (float*)alloc(524288);
    float*  Cm   = (float*)alloc(524288);
    float*  Hb   = (float*)alloc(8388608);
    float*  sdtb = (float*)alloc(262144);
    float*  yf   = (float*)alloc(8388608);
    float*  yb   = (float*)alloc(8388608);
    ushort* hfH  = (ushort*)alloc(2097152);
    ushort* hfL  = (ushort*)alloc(2097152);

    prep_k<<<864, 256, 0, stream>>>(pe_w, Win, Wx, Wdt, Wout, pu_w, mask, wH, wL, mbuf);
    embed_ln_k<<<256, 256, 0, stream>>>(ks, wH, wL, pe_b, cond_band, cond_rad, cond_mask, mbuf,
                                        ln_g, ln_b, fn_g, fn_b, h_, hnH, hnL);
    win_k<<<dim3(64, 8), 256, 0, stream>>>(hnH, hnL, wH, wL, bin_, xp, sz);
    conv_k<<<2048, 256, 0, stream>>>(xp, convw, convb, xc);
    proj_k<<<dim3(64, 5), 256, 0, stream>>>(xc, wH, wL, bdt, mbuf, edt, eB, eC, wr, wm, dt, Bm, Cm);
    scan_k<0><<<dim3(NCh, 2), 256, 0, stream>>>(dt, xc, Bm, Cm, Alog, Hb, sdtb, nullptr, nullptr);
    combine_k<<<32, 256, 0, stream>>>(Hb, sdtb, Alog);
    scan_k<1><<<dim3(NCh, 2), 256, 0, stream>>>(dt, xc, Bm, Cm, Alog, Hb, sdtb, yf, yb);
    wout_k<<<dim3(128, 2), 256, 0, stream>>>(yf, yb, xc, sz, Dp, wH, wL, bout, h_, hfH, hfL);
    unembed_k<<<dim3(128, 2), 256, 0, stream>>>(hfH, hfL, wH, wL, pu_b, ks, out);
}

// Round 5
// 258.822 us; speedup vs baseline: 1.5551x; 1.0870x over previous
//
#include <hip/hip_runtime.h>
#include <hip/hip_bf16.h>

#define L_TOK 8192
#define NCh 256   // scan chunks
#define CLh 32    // chunk length
#define LOG2E 1.44269504088896f

typedef short bf16x8 __attribute__((ext_vector_type(8)));
typedef float f32x4 __attribute__((ext_vector_type(4)));

static __device__ __forceinline__ float nexp2(float x) {
#if __has_builtin(__builtin_amdgcn_exp2f)
    return __builtin_amdgcn_exp2f(x);
#else
    return exp2f(x);
#endif
}
static __device__ __forceinline__ float sigm(float x) {   // 1/(1+e^-x)
    return 1.f / (1.f + nexp2(-x * LOG2E));
}

static __device__ __forceinline__ ushort f2bf(float x) {
    union { float f; uint u; } v; v.f = x;
    uint r = v.u + 0x7fffu + ((v.u >> 16) & 1u);
    return (ushort)(r >> 16);
}
static __device__ __forceinline__ float bf2f(ushort h) {
    union { float f; uint u; } v; v.u = ((uint)h) << 16;
    return v.f;
}
static __device__ __forceinline__ void f2hl(float x, ushort* hi, ushort* lo) {
    ushort h = f2bf(x);
    *hi = h;
    *lo = f2bf(x - bf2f(h));
}

// weight regions in wH/wL (ushort elems), all K-major [n][k]:
#define W_PE   0
#define W_WIN  16384
#define W_WOUT 81920
#define W_PU   114688
#define W_PROJ 131072
#define W_TOT  212992

// ---------------------------------------------------------------------------
// prep: weights -> bf16 hi/lo (with transposes + Wx@Wdt fusion) ; maskpool
__global__ __launch_bounds__(256) void prep_k(const float* __restrict__ pe_w, const float* __restrict__ Win,
                                              const float* __restrict__ Wx, const float* __restrict__ Wdt,
                                              const float* __restrict__ Wout, const float* __restrict__ pu_w,
                                              const float* __restrict__ mask,
                                              ushort* __restrict__ wH, ushort* __restrict__ wL,
                                              float* __restrict__ mbuf) {
    int b = blockIdx.x;
    if (b >= 832) {  // maskpool
        int l = (b - 832) * 256 + threadIdx.x;
        int xg = l >> 8, yg = (l >> 3) & 31, zg = l & 7;
        float s = 0.f;
        for (int i2 = 0; i2 < 2; ++i2)
            for (int j2 = 0; j2 < 2; ++j2)
                for (int k2 = 0; k2 < 2; ++k2)
                    s += mask[(2 * xg + i2) * 1024 + (2 * yg + j2) * 16 + 2 * zg + k2];
        s *= 0.125f;
        mbuf[l] = fminf(fmaxf(s, 0.f), 1.f);
        return;
    }
    int i = b * 256 + threadIdx.x;  // < 212992
    float v;
    if (i < 16384) {
        v = pe_w[i];
    } else if (i < 81920) {
        int j = i - 16384; int n = j >> 7, k = j & 127;
        v = Win[k * 512 + n];
    } else if (i < 114688) {
        int j = i - 81920; int n = j >> 8, k = j & 255;
        v = Wout[k * 128 + n];
    } else if (i < 131072) {
        int j = i - 114688; int n = j >> 7, k = j & 127;
        v = pu_w[k * 128 + n];
    } else {
        int j = i - 131072; int n = j >> 8, k = j & 255;
        if (n < 256) {
            float s = 0.f;
#pragma unroll
            for (int r = 0; r < 8; ++r) s += Wx[k * 40 + r] * Wdt[r * 256 + n];
            v = s;
        } else if (n < 288) {
            v = Wx[k * 40 + 8 + (n - 256)];
        } else {
            v = 0.f;
        }
    }
    ushort h, lo; f2hl(v, &h, &lo);
    wH[i] = h; wL[i] = lo;
}

// ---------------------------------------------------------------------------
// fused: gather patches -> embed GEMM (+pe_b +cond) -> LN -> h_ ; LN2 -> hn hi/lo
__global__ __launch_bounds__(256) void embed_ln_k(const float* __restrict__ ks,
                                                  const ushort* __restrict__ wH, const ushort* __restrict__ wL,
                                                  const float* __restrict__ pe_b, const float* __restrict__ cond_band,
                                                  const float* __restrict__ cond_rad, const float* __restrict__ cond_mask,
                                                  const float* __restrict__ mbuf,
                                                  const float* __restrict__ ln_g, const float* __restrict__ ln_b,
                                                  const float* __restrict__ fn_g, const float* __restrict__ fn_b,
                                                  float* __restrict__ h_,
                                                  ushort* __restrict__ hnH, ushort* __restrict__ hnL) {
    __shared__ __align__(16) char smem[46080];
    ushort (*AsH)[72] = (ushort(*)[72])(smem);
    ushort (*AsL)[72] = (ushort(*)[72])(smem + 4608);
    ushort (*BsH)[72] = (ushort(*)[72])(smem + 9216);
    ushort (*BsL)[72] = (ushort(*)[72])(smem + 27648);
    float  (*Cs)[132] = (float(*)[132])(smem);

    const int tid = threadIdx.x;
    const int lane = tid & 63, wn = tid >> 6;
    const int ln = lane & 15, q = lane >> 4;
    const int mb = blockIdx.x * 32;

    f32x4 acc[2][2];
#pragma unroll
    for (int rb = 0; rb < 2; ++rb)
#pragma unroll
        for (int cb = 0; cb < 2; ++cb) acc[rb][cb] = (f32x4){0.f, 0.f, 0.f, 0.f};

    for (int kc = 0; kc < 128; kc += 64) {
        __syncthreads();
        for (int u = tid; u < 2048; u += 256) {
            int r = u >> 6, kk = u & 63;
            int l = mb + r, k = kc + kk;
            int cc = k >> 3, ijk = k & 7;
            int xg = l >> 8, yg = (l >> 3) & 31, zg = l & 7;
            int i2 = (ijk >> 2) & 1, j2 = (ijk >> 1) & 1, k2 = ijk & 1;
            float v = ks[cc * 65536 + (2 * xg + i2) * 1024 + (2 * yg + j2) * 16 + 2 * zg + k2];
            ushort h, lo; f2hl(v, &h, &lo);
            AsH[r][kk] = h; AsL[r][kk] = lo;
        }
        for (int u = tid; u < 1024; u += 256) {
            int n = u >> 3, g = u & 7;
            *(uint4*)&BsH[n][g * 8] = *(const uint4*)&wH[W_PE + n * 128 + kc + g * 8];
            *(uint4*)&BsL[n][g * 8] = *(const uint4*)&wL[W_PE + n * 128 + kc + g * 8];
        }
        __syncthreads();
#pragma unroll
        for (int ks_ = 0; ks_ < 64; ks_ += 32) {
            const int kk = ks_ + q * 8;
            bf16x8 ah[2], al[2], bh[2], bl[2];
#pragma unroll
            for (int rb = 0; rb < 2; ++rb) {
                ah[rb] = *(const bf16x8*)&AsH[rb * 16 + ln][kk];
                al[rb] = *(const bf16x8*)&AsL[rb * 16 + ln][kk];
            }
#pragma unroll
            for (int cb = 0; cb < 2; ++cb) {
                bh[cb] = *(const bf16x8*)&BsH[wn * 32 + cb * 16 + ln][kk];
                bl[cb] = *(const bf16x8*)&BsL[wn * 32 + cb * 16 + ln][kk];
            }
#pragma unroll
            for (int rb = 0; rb < 2; ++rb)
#pragma unroll
                for (int cb = 0; cb < 2; ++cb) {
                    acc[rb][cb] = __builtin_amdgcn_mfma_f32_16x16x32_bf16(ah[rb], bh[cb], acc[rb][cb], 0, 0, 0);
                    acc[rb][cb] = __builtin_amdgcn_mfma_f32_16x16x32_bf16(ah[rb], bl[cb], acc[rb][cb], 0, 0, 0);
                    acc[rb][cb] = __builtin_amdgcn_mfma_f32_16x16x32_bf16(al[rb], bh[cb], acc[rb][cb], 0, 0, 0);
                }
        }
    }
    __syncthreads();
#pragma unroll
    for (int rb = 0; rb < 2; ++rb) {
#pragma unroll
        for (int cb = 0; cb < 2; ++cb) {
#pragma unroll
            for (int r = 0; r < 4; ++r) {
                int row = rb * 16 + q * 4 + r;
                int col = wn * 32 + cb * 16 + ln;
                int l = mb + row;
                float rho = (float)l * (1.0f / 8191.0f);
                int band = min(7, (int)(rho * 8.0f));
                Cs[row][col] = acc[rb][cb][r] + pe_b[col] + cond_band[band * 128 + col]
                               + rho * cond_rad[col] + mbuf[l] * cond_mask[col];
            }
        }
    }
    __syncthreads();
    {
        int row = tid >> 3, j = tid & 7;
        int l = mb + row;
        float v16[16];
        float s = 0.f, s2 = 0.f;
#pragma unroll
        for (int i = 0; i < 16; ++i) {
            float v = Cs[row][j * 16 + i];
            v16[i] = v; s += v; s2 += v * v;
        }
#pragma unroll
        for (int o = 1; o < 8; o <<= 1) { s += __shfl_xor(s, o, 8); s2 += __shfl_xor(s2, o, 8); }
        float mu = s * (1.f / 128.f);
        float var = s2 * (1.f / 128.f) - mu * mu;
        float rstd = rsqrtf(fmaxf(var, 0.f) + 1e-5f);
        float hv[16];
        s = 0.f; s2 = 0.f;
#pragma unroll
        for (int i = 0; i < 16; ++i) {
            int col = j * 16 + i;
            float h = (v16[i] - mu) * rstd * ln_g[col] + ln_b[col];
            hv[i] = h; s += h; s2 += h * h;
        }
#pragma unroll
        for (int i = 0; i < 16; i += 4)
            *(float4*)&h_[(size_t)l * 128 + j * 16 + i] = make_float4(hv[i], hv[i + 1], hv[i + 2], hv[i + 3]);
#pragma unroll
        for (int o = 1; o < 8; o <<= 1) { s += __shfl_xor(s, o, 8); s2 += __shfl_xor(s2, o, 8); }
        mu = s * (1.f / 128.f);
        var = s2 * (1.f / 128.f) - mu * mu;
        rstd = rsqrtf(fmaxf(var, 0.f) + 1e-5f);
        union { ushort u[16]; uint4 v4[2]; } oh, ol;
#pragma unroll
        for (int i = 0; i < 16; ++i) {
            int col = j * 16 + i;
            float o2 = (hv[i] - mu) * rstd * fn_g[col] + fn_b[col];
            ushort hh, ll; f2hl(o2, &hh, &ll);
            oh.u[i] = hh; ol.u[i] = ll;
        }
        *(uint4*)&hnH[(size_t)l * 128 + j * 16] = oh.v4[0];
        *(uint4*)&hnH[(size_t)l * 128 + j * 16 + 8] = oh.v4[1];
        *(uint4*)&hnL[(size_t)l * 128 + j * 16] = ol.v4[0];
        *(uint4*)&hnL[(size_t)l * 128 + j * 16 + 8] = ol.v4[1];
    }
}

// ---------------------------------------------------------------------------
// Win GEMM: xz = hn @ Win + bin ; xp (cols<256) raw, sz (cols>=256) = silu
__global__ __launch_bounds__(256) void win_k(const ushort* __restrict__ Ah, const ushort* __restrict__ Al,
                                             const ushort* __restrict__ wH, const ushort* __restrict__ wL,
                                             const float* __restrict__ bin_,
                                             float* __restrict__ xp, float* __restrict__ sz) {
    __shared__ ushort AsH[128][72], AsL[128][72];
    __shared__ ushort BsH[64][72], BsL[64][72];
    const int tid = threadIdx.x;
    const int lane = tid & 63, wave = tid >> 6;
    const int wm = wave & 1, wn = wave >> 1;
    const int ln = lane & 15, q = lane >> 4;
    const int mb = blockIdx.x * 128, nb = blockIdx.y * 64;

    f32x4 acc[4][2];
#pragma unroll
    for (int rb = 0; rb < 4; ++rb)
#pragma unroll
        for (int cb = 0; cb < 2; ++cb) acc[rb][cb] = (f32x4){0.f, 0.f, 0.f, 0.f};

    for (int kc = 0; kc < 128; kc += 64) {
        __syncthreads();
        for (int u = tid; u < 1024; u += 256) {
            int r = u >> 3, g = u & 7;
            size_t go = (size_t)(mb + r) * 128 + kc + g * 8;
            *(uint4*)&AsH[r][g * 8] = *(const uint4*)&Ah[go];
            *(uint4*)&AsL[r][g * 8] = *(const uint4*)&Al[go];
        }
        for (int u = tid; u < 512; u += 256) {
            int n = u >> 3, g = u & 7;
            size_t go = (size_t)(W_WIN) + (size_t)(nb + n) * 128 + kc + g * 8;
            *(uint4*)&BsH[n][g * 8] = *(const uint4*)&wH[go];
            *(uint4*)&BsL[n][g * 8] = *(const uint4*)&wL[go];
        }
        __syncthreads();
#pragma unroll
        for (int ks_ = 0; ks_ < 64; ks_ += 32) {
            const int kk = ks_ + q * 8;
            bf16x8 ah[4], al[4], bh[2], bl[2];
#pragma unroll
            for (int rb = 0; rb < 4; ++rb) {
                ah[rb] = *(const bf16x8*)&AsH[wm * 64 + rb * 16 + ln][kk];
                al[rb] = *(const bf16x8*)&AsL[wm * 64 + rb * 16 + ln][kk];
            }
#pragma unroll
            for (int cb = 0; cb < 2; ++cb) {
                bh[cb] = *(const bf16x8*)&BsH[wn * 32 + cb * 16 + ln][kk];
                bl[cb] = *(const bf16x8*)&BsL[wn * 32 + cb * 16 + ln][kk];
            }
#pragma unroll
            for (int rb = 0; rb < 4; ++rb)
#pragma unroll
                for (int cb = 0; cb < 2; ++cb) {
                    acc[rb][cb] = __builtin_amdgcn_mfma_f32_16x16x32_bf16(ah[rb], bh[cb], acc[rb][cb], 0, 0, 0);
                    acc[rb][cb] = __builtin_amdgcn_mfma_f32_16x16x32_bf16(ah[rb], bl[cb], acc[rb][cb], 0, 0, 0);
                    acc[rb][cb] = __builtin_amdgcn_mfma_f32_16x16x32_bf16(al[rb], bh[cb], acc[rb][cb], 0, 0, 0);
                }
        }
    }
#pragma unroll
    for (int rb = 0; rb < 4; ++rb)
#pragma unroll
        for (int cb = 0; cb < 2; ++cb)
#pragma unroll
            for (int r = 0; r < 4; ++r) {
                int l = mb + wm * 64 + rb * 16 + q * 4 + r;
                int col = nb + wn * 32 + cb * 16 + ln;
                float v = acc[rb][cb][r] + bin_[col];
                if (col < 256) {
                    xp[(size_t)l * 256 + col] = v;
                } else {
                    sz[(size_t)l * 256 + (col - 256)] = v * sigm(v);
                }
            }
}

// causal depthwise conv (4 taps) + SiLU, float4 over channels
__global__ __launch_bounds__(256) void conv_k(const float* __restrict__ xp, const float* __restrict__ convw,
                                              const float* __restrict__ convb, float* __restrict__ xc) {
    int id = blockIdx.x * 256 + threadIdx.x;   // < 524288
    int l = id >> 6, e4 = (id & 63) * 4;
    float4 cw[4];
#pragma unroll
    for (int j = 0; j < 4; ++j) cw[j] = *(const float4*)&convw[(e4 + j) * 4];
    float4 cb = *(const float4*)&convb[e4];
    float o[4] = {cb.x, cb.y, cb.z, cb.w};
#pragma unroll
    for (int k = 0; k < 4; ++k) {
        int lp = l - 3 + k;
        if (lp >= 0) {
            float4 t = *(const float4*)&xp[(size_t)lp * 256 + e4];
            o[0] += t.x * ((const float*)&cw[0])[k];
            o[1] += t.y * ((const float*)&cw[1])[k];
            o[2] += t.z * ((const float*)&cw[2])[k];
            o[3] += t.w * ((const float*)&cw[3])[k];
        }
    }
    float4 r;
    r.x = o[0] * sigm(o[0]);
    r.y = o[1] * sigm(o[1]);
    r.z = o[2] * sigm(o[2]);
    r.w = o[3] * sigm(o[3]);
    *(float4*)&xc[(size_t)l * 256 + e4] = r;
}

// ---------------------------------------------------------------------------
// proj GEMM: xc @ [Wfused | WxBC] (N=288, padded 320); epilogue -> dt / Bm / Cm
__global__ __launch_bounds__(256) void proj_k(const float* __restrict__ xc,
                                              const ushort* __restrict__ wH, const ushort* __restrict__ wL,
                                              const float* __restrict__ bdt, const float* __restrict__ mbuf,
                                              const float* __restrict__ edt, const float* __restrict__ eB,
                                              const float* __restrict__ eC, const float* __restrict__ wr,
                                              const float* __restrict__ wm,
                                              float* __restrict__ dt, float* __restrict__ Bm, float* __restrict__ Cm) {
    __shared__ ushort AsH[128][72], AsL[128][72];
    __shared__ ushort BsH[64][72], BsL[64][72];
    const int tid = threadIdx.x;
    const int lane = tid & 63, wave = tid >> 6;
    const int wm_ = wave & 1, wn = wave >> 1;
    const int ln = lane & 15, q = lane >> 4;
    const int mb = blockIdx.x * 128, nb = blockIdx.y * 64;

    f32x4 acc[4][2];
#pragma unroll
    for (int rb = 0; rb < 4; ++rb)
#pragma unroll
        for (int cb = 0; cb < 2; ++cb) acc[rb][cb] = (f32x4){0.f, 0.f, 0.f, 0.f};

    for (int kc = 0; kc < 256; kc += 64) {
        __syncthreads();
        for (int u = tid; u < 2048; u += 256) {
            int r = u >> 4, kq = u & 15;
            float4 v = *(const float4*)&xc[(size_t)(mb + r) * 256 + kc + kq * 4];
            union { ushort u[4]; uint2 v2; } hh, ll;
            f2hl(v.x, &hh.u[0], &ll.u[0]); f2hl(v.y, &hh.u[1], &ll.u[1]);
            f2hl(v.z, &hh.u[2], &ll.u[2]); f2hl(v.w, &hh.u[3], &ll.u[3]);
            *(uint2*)&AsH[r][kq * 4] = hh.v2;
            *(uint2*)&AsL[r][kq * 4] = ll.v2;
        }
        for (int u = tid; u < 512; u += 256) {
            int n = u >> 3, g = u & 7;
            size_t go = (size_t)(W_PROJ) + (size_t)(nb + n) * 256 + kc + g * 8;
            *(uint4*)&BsH[n][g * 8] = *(const uint4*)&wH[go];
            *(uint4*)&BsL[n][g * 8] = *(const uint4*)&wL[go];
        }
        __syncthreads();
#pragma unroll
        for (int ks_ = 0; ks_ < 64; ks_ += 32) {
            const int kk = ks_ + q * 8;
            bf16x8 ah[4], al[4], bh[2], bl[2];
#pragma unroll
            for (int rb = 0; rb < 4; ++rb) {
                ah[rb] = *(const bf16x8*)&AsH[wm_ * 64 + rb * 16 + ln][kk];
                al[rb] = *(const bf16x8*)&AsL[wm_ * 64 + rb * 16 + ln][kk];
            }
#pragma unroll
            for (int cb = 0; cb < 2; ++cb) {
                bh[cb] = *(const bf16x8*)&BsH[wn * 32 + cb * 16 + ln][kk];
                bl[cb] = *(const bf16x8*)&BsL[wn * 32 + cb * 16 + ln][kk];
            }
#pragma unroll
            for (int rb = 0; rb < 4; ++rb)
#pragma unroll
                for (int cb = 0; cb < 2; ++cb) {
                    acc[rb][cb] = __builtin_amdgcn_mfma_f32_16x16x32_bf16(ah[rb], bh[cb], acc[rb][cb], 0, 0, 0);
                    acc[rb][cb] = __builtin_amdgcn_mfma_f32_16x16x32_bf16(ah[rb], bl[cb], acc[rb][cb], 0, 0, 0);
                    acc[rb][cb] = __builtin_amdgcn_mfma_f32_16x16x32_bf16(al[rb], bh[cb], acc[rb][cb], 0, 0, 0);
                }
        }
    }
#pragma unroll
    for (int rb = 0; rb < 4; ++rb)
#pragma unroll
        for (int cb = 0; cb < 2; ++cb)
#pragma unroll
            for (int r = 0; r < 4; ++r) {
                int l = mb + wm_ * 64 + rb * 16 + q * 4 + r;
                int col = nb + wn * 32 + cb * 16 + ln;
                float v = acc[rb][cb][r];
                float rho = (float)l * (1.0f / 8191.0f);
                int band = min(7, (int)(rho * 8.0f));
                float mv = mbuf[l];
                if (col < 256) {
                    float sc0 = 2.0f * sigm(edt[band] + wr[0] * rho + wm[0] * mv);
                    float v2 = v + bdt[col];
                    float sp = (v2 > 20.f) ? v2 : log1pf(expf(v2));
                    dt[(size_t)l * 256 + col] = sp * sc0;
                } else if (col < 272) {
                    float sc1 = 2.0f * sigm(eB[band] + wr[1] * rho + wm[1] * mv);
                    Bm[(size_t)l * 16 + (col - 256)] = v * sc1;
                } else if (col < 288) {
                    float sc2 = 2.0f * sigm(eC[band] + wr[2] * rho + wm[2] * mv);
                    Cm[(size_t)l * 16 + (col - 272)] = v * sc2;
                }
            }
}

// ---------------------------------------------------------------------------
// scan, one lane per channel e, h[16] in registers; 8-step batched prefetch,
// native v_exp_f32.
template <int PHASE>
__global__ __launch_bounds__(256) void scan_k(const float* __restrict__ dt, const float* __restrict__ xc,
                                              const float* __restrict__ Bm, const float* __restrict__ Cm,
                                              const float* __restrict__ Alog,
                                              float* __restrict__ Hb, float* __restrict__ sdtb,
                                              float* __restrict__ yf, float* __restrict__ yb) {
    const int c = blockIdx.x, dir = blockIdx.y, e = threadIdx.x;
    __shared__ float bms[CLh][16];
    __shared__ float cms[CLh][16];
    for (int idx = e; idx < CLh * 16; idx += 256) {
        bms[idx >> 4][idx & 15] = Bm[c * (CLh * 16) + idx];
        if (PHASE == 1) cms[idx >> 4][idx & 15] = Cm[c * (CLh * 16) + idx];
    }
    float A2[16], iv[16], h[16];
#pragma unroll
    for (int n = 0; n < 16; ++n) {
        float ea = nexp2(Alog[e * 16 + n] * LOG2E);   // = exp(Alog)
        A2[n] = -ea * LOG2E;
        iv[n] = -1.0f / ea;                           // 1/A
    }
    const size_t hofs = (size_t)(dir * NCh + c) * 4096 + e * 16;
    if (PHASE == 0) {
#pragma unroll
        for (int n = 0; n < 16; ++n) h[n] = 0.f;
    } else {
#pragma unroll
        for (int j = 0; j < 4; ++j) {
            float4 hv = *(const float4*)&Hb[hofs + 4 * j];
            h[4 * j] = hv.x; h[4 * j + 1] = hv.y; h[4 * j + 2] = hv.z; h[4 * j + 3] = hv.w;
        }
    }
    const int base = c * CLh;
    float cu[8], cx[8], nu[8], nx[8];
#pragma unroll
    for (int j = 0; j < 8; ++j) {
        int p = dir ? (CLh - 1 - j) : j;
        cu[j] = dt[(size_t)(base + p) * 256 + e];
        cx[j] = xc[(size_t)(base + p) * 256 + e];
    }
    __syncthreads();
    float sdt = 0.f;
    float* __restrict__ yp = dir ? yb : yf;
#pragma unroll
    for (int g = 0; g < CLh / 8; ++g) {
        if (g + 1 < CLh / 8) {
#pragma unroll
            for (int j = 0; j < 8; ++j) {
                int s = (g + 1) * 8 + j;
                int p = dir ? (CLh - 1 - s) : s;
                nu[j] = dt[(size_t)(base + p) * 256 + e];
                nx[j] = xc[(size_t)(base + p) * 256 + e];
            }
        }
#pragma unroll
        for (int j = 0; j < 8; ++j) {
            int s = g * 8 + j;
            int p = dir ? (CLh - 1 - s) : s;
            float u = cu[j], xv = cx[j];
            union { float4 v[4]; float f[16]; } bb, cc;
            const float4* bp = (const float4*)&bms[p][0];
            bb.v[0] = bp[0]; bb.v[1] = bp[1]; bb.v[2] = bp[2]; bb.v[3] = bp[3];
            if (PHASE == 1) {
                const float4* cp = (const float4*)&cms[p][0];
                cc.v[0] = cp[0]; cc.v[1] = cp[1]; cc.v[2] = cp[2]; cc.v[3] = cp[3];
            }
            float y = 0.f;
#pragma unroll
            for (int n = 0; n < 16; ++n) {
                float a = nexp2(A2[n] * u);
                float w = xv * bb.f[n] * iv[n];
                float t = h[n] + w;
                h[n] = a * t - w;
                if (PHASE == 1) y += h[n] * cc.f[n];
            }
            if (PHASE == 0) sdt += u;
            if (PHASE == 1) yp[(size_t)(base + p) * 256 + e] = y;
        }
#pragma unroll
        for (int j = 0; j < 8; ++j) { cu[j] = nu[j]; cx[j] = nx[j]; }
    }
    if (PHASE == 0) {
#pragma unroll
        for (int j = 0; j < 4; ++j) {
            float4 hv = make_float4(h[4 * j], h[4 * j + 1], h[4 * j + 2], h[4 * j + 3]);
            *(float4*)&Hb[hofs + 4 * j] = hv;
        }
        if (dir == 0) sdtb[c * 256 + e] = sdt;
    }
}

// chunk-level scan, in place: Hb[c] <- prefix state entering chunk c
__global__ __launch_bounds__(256) void combine_k(float* __restrict__ Hb, const float* __restrict__ sdtb,
                                                 const float* __restrict__ Alog) {
    int id = blockIdx.x * 256 + threadIdx.x;   // < 8192
    int dir = id >> 12, en = id & 4095, e = en >> 4;
    float A2 = -nexp2(Alog[en] * LOG2E) * LOG2E;
    float hi = 0.f;
    for (int g = 0; g < NCh / 8; ++g) {
        float Pv[8], qv[8];
#pragma unroll
        for (int j = 0; j < 8; ++j) {
            int c = dir ? (NCh - 1 - (g * 8 + j)) : (g * 8 + j);
            Pv[j] = sdtb[c * 256 + e];
            qv[j] = Hb[(size_t)(dir * NCh + c) * 4096 + en];
        }
#pragma unroll
        for (int j = 0; j < 8; ++j) {
            int c = dir ? (NCh - 1 - (g * 8 + j)) : (g * 8 + j);
            float P = nexp2(A2 * Pv[j]);
            Hb[(size_t)(dir * NCh + c) * 4096 + en] = hi;
            hi = P * hi + qv[j];
        }
    }
}

// ---------------------------------------------------------------------------
// Wout GEMM with gate fused in A-staging: A = (yf+yb+D*xc)*sz -> hi/lo
__global__ __launch_bounds__(256) void wout_k(const float* __restrict__ yf, const float* __restrict__ yb,
                                              const float* __restrict__ xc, const float* __restrict__ sz,
                                              const float* __restrict__ Dp,
                                              const ushort* __restrict__ wH, const ushort* __restrict__ wL,
                                              const float* __restrict__ bout, const float* __restrict__ h_,
                                              ushort* __restrict__ hfH, ushort* __restrict__ hfL) {
    __shared__ ushort AsH[64][72], AsL[64][72];
    __shared__ ushort BsH[64][72], BsL[64][72];
    const int tid = threadIdx.x;
    const int lane = tid & 63, wave = tid >> 6;
    const int wm = wave & 1, wn = wave >> 1;
    const int ln = lane & 15, q = lane >> 4;
    const int mb = blockIdx.x * 64, nb = blockIdx.y * 64;

    f32x4 acc[2][2];
#pragma unroll
    for (int rb = 0; rb < 2; ++rb)
#pragma unroll
        for (int cb = 0; cb < 2; ++cb) acc[rb][cb] = (f32x4){0.f, 0.f, 0.f, 0.f};

    for (int kc = 0; kc < 256; kc += 64) {
        __syncthreads();
        for (int u = tid; u < 1024; u += 256) {
            int r = u >> 4, kq = u & 15;
            size_t go = (size_t)(mb + r) * 256 + kc + kq * 4;
            float4 a = *(const float4*)&yf[go];
            float4 b = *(const float4*)&yb[go];
            float4 x = *(const float4*)&xc[go];
            float4 s = *(const float4*)&sz[go];
            float4 d = *(const float4*)&Dp[kc + kq * 4];
            float v0 = (a.x + b.x + d.x * x.x) * s.x;
            float v1 = (a.y + b.y + d.y * x.y) * s.y;
            float v2 = (a.z + b.z + d.z * x.z) * s.z;
            float v3 = (a.w + b.w + d.w * x.w) * s.w;
            union { ushort u[4]; uint2 v2; } hh, ll;
            f2hl(v0, &hh.u[0], &ll.u[0]); f2hl(v1, &hh.u[1], &ll.u[1]);
            f2hl(v2, &hh.u[2], &ll.u[2]); f2hl(v3, &hh.u[3], &ll.u[3]);
            *(uint2*)&AsH[r][kq * 4] = hh.v2;
            *(uint2*)&AsL[r][kq * 4] = ll.v2;
        }
        for (int u = tid; u < 512; u += 256) {
            int n = u >> 3, g = u & 7;
            size_t go = (size_t)(W_WOUT) + (size_t)(nb + n) * 256 + kc + g * 8;
            *(uint4*)&BsH[n][g * 8] = *(const uint4*)&wH[go];
            *(uint4*)&BsL[n][g * 8] = *(const uint4*)&wL[go];
        }
        __syncthreads();
#pragma unroll
        for (int ks_ = 0; ks_ < 64; ks_ += 32) {
            const int kk = ks_ + q * 8;
            bf16x8 ah[2], al[2], bh[2], bl[2];
#pragma unroll
            for (int rb = 0; rb < 2; ++rb) {
                ah[rb] = *(const bf16x8*)&AsH[wm * 32 + rb * 16 + ln][kk];
                al[rb] = *(const bf16x8*)&AsL[wm * 32 + rb * 16 + ln][kk];
            }
#pragma unroll
            for (int cb = 0; cb < 2; ++cb) {
                bh[cb] = *(const bf16x8*)&BsH[wn * 32 + cb * 16 + ln][kk];
                bl[cb] = *(const bf16x8*)&BsL[wn * 32 + cb * 16 + ln][kk];
            }
#pragma unroll
            for (int rb = 0; rb < 2; ++rb)
#pragma unroll
                for (int cb = 0; cb < 2; ++cb) {
                    acc[rb][cb] = __builtin_amdgcn_mfma_f32_16x16x32_bf16(ah[rb], bh[cb], acc[rb][cb], 0, 0, 0);
                    acc[rb][cb] = __builtin_amdgcn_mfma_f32_16x16x32_bf16(ah[rb], bl[cb], acc[rb][cb], 0, 0, 0);
                    acc[rb][cb] = __builtin_amdgcn_mfma_f32_16x16x32_bf16(al[rb], bh[cb], acc[rb][cb], 0, 0, 0);
                }
        }
    }
#pragma unroll
    for (int rb = 0; rb < 2; ++rb)
#pragma unroll
        for (int cb = 0; cb < 2; ++cb)
#pragma unroll
            for (int r = 0; r < 4; ++r) {
                int l = mb + wm * 32 + rb * 16 + q * 4 + r;
                int col = nb + wn * 32 + cb * 16 + ln;
                float v = acc[rb][cb][r] + bout[col] + h_[(size_t)l * 128 + col];
                ushort hh, ll; f2hl(v, &hh, &ll);
                hfH[(size_t)l * 128 + col] = hh;
                hfL[(size_t)l * 128 + col] = ll;
            }
}

// unembed GEMM: out = hf @ pu^T + pu_b + ks (scattered)
__global__ __launch_bounds__(256) void unembed_k(const ushort* __restrict__ Ah, const ushort* __restrict__ Al,
                                                 const ushort* __restrict__ wH, const ushort* __restrict__ wL,
                                                 const float* __restrict__ pu_b, const float* __restrict__ ks,
                                                 float* __restrict__ out) {
    __shared__ ushort AsH[64][72], AsL[64][72];
    __shared__ ushort BsH[64][72], BsL[64][72];
    const int tid = threadIdx.x;
    const int lane = tid & 63, wave = tid >> 6;
    const int wm = wave & 1, wn = wave >> 1;
    const int ln = lane & 15, q = lane >> 4;
    const int mb = blockIdx.x * 64, nb = blockIdx.y * 64;

    f32x4 acc[2][2];
#pragma unroll
    for (int rb = 0; rb < 2; ++rb)
#pragma unroll
        for (int cb = 0; cb < 2; ++cb) acc[rb][cb] = (f32x4){0.f, 0.f, 0.f, 0.f};

    for (int kc = 0; kc < 128; kc += 64) {
        __syncthreads();
        for (int u = tid; u < 512; u += 256) {
            int r = u >> 3, g = u & 7;
            size_t go = (size_t)(mb + r) * 128 + kc + g * 8;
            *(uint4*)&AsH[r][g * 8] = *(const uint4*)&Ah[go];
            *(uint4*)&AsL[r][g * 8] = *(const uint4*)&Al[go];
        }
        for (int u = tid; u < 512; u += 256) {
            int n = u >> 3, g = u & 7;
            size_t go = (size_t)(W_PU) + (size_t)(nb + n) * 128 + kc + g * 8;
            *(uint4*)&BsH[n][g * 8] = *(const uint4*)&wH[go];
            *(uint4*)&BsL[n][g * 8] = *(const uint4*)&wL[go];
        }
        __syncthreads();
#pragma unroll
        for (int ks_ = 0; ks_ < 64; ks_ += 32) {
            const int kk = ks_ + q * 8;
            bf16x8 ah[2], al[2], bh[2], bl[2];
#pragma unroll
            for (int rb = 0; rb < 2; ++rb) {
                ah[rb] = *(const bf16x8*)&AsH[wm * 32 + rb * 16 + ln][kk];
                al[rb] = *(const bf16x8*)&AsL[wm * 32 + rb * 16 + ln][kk];
            }
#pragma unroll
            for (int cb = 0; cb < 2; ++cb) {
                bh[cb] = *(const bf16x8*)&BsH[wn * 32 + cb * 16 + ln][kk];
                bl[cb] = *(const bf16x8*)&BsL[wn * 32 + cb * 16 + ln][kk];
            }
#pragma unroll
            for (int rb = 0; rb < 2; ++rb)
#pragma unroll
                for (int cb = 0; cb < 2; ++cb) {
                    acc[rb][cb] = __builtin_amdgcn_mfma_f32_16x16x32_bf16(ah[rb], bh[cb], acc[rb][cb], 0, 0, 0);
                    acc[rb][cb] = __builtin_amdgcn_mfma_f32_16x16x32_bf16(ah[rb], bl[cb], acc[rb][cb], 0, 0, 0);
                    acc[rb][cb] = __builtin_amdgcn_mfma_f32_16x16x32_bf16(al[rb], bh[cb], acc[rb][cb], 0, 0, 0);
                }
        }
    }
#pragma unroll
    for (int rb = 0; rb < 2; ++rb)
#pragma unroll
        for (int cb = 0; cb < 2; ++cb)
#pragma unroll
            for (int r = 0; r < 4; ++r) {
                int l = mb + wm * 32 + rb * 16 + q * 4 + r;
                int col = nb + wn * 32 + cb * 16 + ln;
                int xg = l >> 8, yg = (l >> 3) & 31, zg = l & 7;
                int c = col >> 3, ijk = col & 7;
                int i2 = (ijk >> 2) & 1, j2 = (ijk >> 1) & 1, k2 = ijk & 1;
                size_t idx = (size_t)((c * 64 + 2 * xg + i2) * 64 + (2 * yg + j2)) * 16 + 2 * zg + k2;
                out[idx] = acc[rb][cb][r] + pu_b[c] + ks[idx];
            }
}

// ---------------------------------------------------------------------------
extern "C" void kernel_launch(void* const* d_in, const int* in_sizes, int n_in,
                              void* d_out, int out_size, void* d_ws, size_t ws_size,
                              hipStream_t stream) {
    const float* ks    = (const float*)d_in[0];
    const float* mask  = (const float*)d_in[1];
    const float* pe_w  = (const float*)d_in[2];
    const float* pe_b  = (const float*)d_in[3];
    const float* pu_w  = (const float*)d_in[4];
    const float* pu_b  = (const float*)d_in[5];
    const float* ln_g  = (const float*)d_in[6];
    const float* ln_b  = (const float*)d_in[7];
    const float* fn_g  = (const float*)d_in[8];
    const float* fn_b  = (const float*)d_in[9];
    const float* cond_band = (const float*)d_in[10];
    const float* cond_rad  = (const float*)d_in[11];
    const float* cond_mask = (const float*)d_in[12];
    const float* Win   = (const float*)d_in[13];
    const float* bin_  = (const float*)d_in[14];
    const float* convw = (const float*)d_in[15];
    const float* convb = (const float*)d_in[16];
    const float* Wx    = (const float*)d_in[17];
    const float* Wdt   = (const float*)d_in[18];
    const float* bdt   = (const float*)d_in[19];
    const float* Alog  = (const float*)d_in[20];
    const float* Dp    = (const float*)d_in[21];
    const float* Wout  = (const float*)d_in[22];
    const float* bout  = (const float*)d_in[23];
    const float* edt   = (const float*)d_in[24];
    const float* eB    = (const float*)d_in[25];
    const float* eC    = (const float*)d_in[26];
    const float* wr    = (const float*)d_in[27];
    const float* wm    = (const float*)d_in[28];
    float* out = (float*)d_out;

    char* base = (char*)d_ws;
    size_t o = 0;
    auto alloc = [&](size_t bytes) { char* p = base + o; o += (bytes + 255) & ~(size_t)255; return p; };
    float*  mbuf = (float*)alloc(32768);
    ushort* wH   = (ushort*)alloc(W_TOT * 2);
    ushort* wL   = (ushort*)alloc(W_TOT * 2);
    float*  h_   = (float*)alloc(4194304);
    ushort* hnH  = (ushort*)alloc(2097152);
    ushort* hnL  = (ushort*)alloc(2097152);
    float*  xp   = (float*)alloc(8388608);
    float*  sz   = (float*)alloc(8388608);
    float*  xc   = (float*)alloc(8388608);
    float*  dt   = (float*)alloc(8388608);
    float*  Bm   = (float*)alloc(524288);
    float*  Cm   = (float*)alloc(524288);
    float*  Hb   = (float*)alloc(8388608);
    float*  sdtb = (float*)alloc(262144);
    float*  yf   = (float*)alloc(8388608);
    float*  yb   = (float*)alloc(8388608);
    ushort* hfH  = (ushort*)alloc(2097152);
    ushort* hfL  = (ushort*)alloc(2097152);

    prep_k<<<864, 256, 0, stream>>>(pe_w, Win, Wx, Wdt, Wout, pu_w, mask, wH, wL, mbuf);
    embed_ln_k<<<256, 256, 0, stream>>>(ks, wH, wL, pe_b, cond_band, cond_rad, cond_mask, mbuf,
                                        ln_g, ln_b, fn_g, fn_b, h_, hnH, hnL);
    win_k<<<dim3(64, 8), 256, 0, stream>>>(hnH, hnL, wH, wL, bin_, xp, sz);
    conv_k<<<2048, 256, 0, stream>>>(xp, convw, convb, xc);
    proj_k<<<dim3(64, 5), 256, 0, stream>>>(xc, wH, wL, bdt, mbuf, edt, eB, eC, wr, wm, dt, Bm, Cm);
    scan_k<0><<<dim3(NCh, 2), 256, 0, stream>>>(dt, xc, Bm, Cm, Alog, Hb, sdtb, nullptr, nullptr);
    combine_k<<<32, 256, 0, stream>>>(Hb, sdtb, Alog);
    scan_k<1><<<dim3(NCh, 2), 256, 0, stream>>>(dt, xc, Bm, Cm, Alog, Hb, sdtb, yf, yb);
    wout_k<<<dim3(128, 2), 256, 0, stream>>>(yf, yb, xc, sz, Dp, wH, wL, bout, h_, hfH, hfL);
    unembed_k<<<dim3(128, 2), 256, 0, stream>>>(hfH, hfL, wH, wL, pu_b, ks, out);
}

// Round 6
// 239.916 us; speedup vs baseline: 1.6776x; 1.0788x over previous
//
#include <hip/hip_runtime.h>
#include <hip/hip_bf16.h>

#define L_TOK 8192
#define NCh 256   // scan chunks
#define CLh 32    // chunk length
#define LOG2E 1.44269504088896f

typedef short bf16x8 __attribute__((ext_vector_type(8)));
typedef float f32x4 __attribute__((ext_vector_type(4)));

static __device__ __forceinline__ float nexp2(float x) {
#if __has_builtin(__builtin_amdgcn_exp2f)
    return __builtin_amdgcn_exp2f(x);
#else
    return exp2f(x);
#endif
}
static __device__ __forceinline__ float sigm(float x) {   // 1/(1+e^-x)
    return 1.f / (1.f + nexp2(-x * LOG2E));
}

static __device__ __forceinline__ ushort f2bf(float x) {
    union { float f; uint u; } v; v.f = x;
    uint r = v.u + 0x7fffu + ((v.u >> 16) & 1u);
    return (ushort)(r >> 16);
}
static __device__ __forceinline__ float bf2f(ushort h) {
    union { float f; uint u; } v; v.u = ((uint)h) << 16;
    return v.f;
}
static __device__ __forceinline__ void f2hl(float x, ushort* hi, ushort* lo) {
    ushort h = f2bf(x);
    *hi = h;
    *lo = f2bf(x - bf2f(h));
}

// weight regions in wH/wL (ushort elems), all K-major [n][k]:
#define W_PE   0
#define W_WIN  16384
#define W_WOUT 81920
#define W_PU   114688
#define W_PROJ 131072
#define W_TOT  212992

// ---------------------------------------------------------------------------
// prep: weights -> bf16 hi/lo (with transposes + Wx@Wdt fusion) ; maskpool
__global__ __launch_bounds__(256) void prep_k(const float* __restrict__ pe_w, const float* __restrict__ Win,
                                              const float* __restrict__ Wx, const float* __restrict__ Wdt,
                                              const float* __restrict__ Wout, const float* __restrict__ pu_w,
                                              const float* __restrict__ mask,
                                              ushort* __restrict__ wH, ushort* __restrict__ wL,
                                              float* __restrict__ mbuf) {
    int b = blockIdx.x;
    if (b >= 832) {  // maskpool
        int l = (b - 832) * 256 + threadIdx.x;
        int xg = l >> 8, yg = (l >> 3) & 31, zg = l & 7;
        float s = 0.f;
        for (int i2 = 0; i2 < 2; ++i2)
            for (int j2 = 0; j2 < 2; ++j2)
                for (int k2 = 0; k2 < 2; ++k2)
                    s += mask[(2 * xg + i2) * 1024 + (2 * yg + j2) * 16 + 2 * zg + k2];
        s *= 0.125f;
        mbuf[l] = fminf(fmaxf(s, 0.f), 1.f);
        return;
    }
    int i = b * 256 + threadIdx.x;  // < 212992
    float v;
    if (i < 16384) {
        v = pe_w[i];
    } else if (i < 81920) {
        int j = i - 16384; int n = j >> 7, k = j & 127;
        v = Win[k * 512 + n];
    } else if (i < 114688) {
        int j = i - 81920; int n = j >> 8, k = j & 255;
        v = Wout[k * 128 + n];
    } else if (i < 131072) {
        int j = i - 114688; int n = j >> 7, k = j & 127;
        v = pu_w[k * 128 + n];
    } else {
        int j = i - 131072; int n = j >> 8, k = j & 255;
        if (n < 256) {
            float s = 0.f;
#pragma unroll
            for (int r = 0; r < 8; ++r) s += Wx[k * 40 + r] * Wdt[r * 256 + n];
            v = s;
        } else if (n < 288) {
            v = Wx[k * 40 + 8 + (n - 256)];
        } else {
            v = 0.f;
        }
    }
    ushort h, lo; f2hl(v, &h, &lo);
    wH[i] = h; wL[i] = lo;
}

// ---------------------------------------------------------------------------
// fused: gather -> embed GEMM (+pe_b +cond) -> LN -> h_ ; LN2 -> hn hi/lo
// tile 16 x 128 (full N), 512 blocks (2/CU), 256 threads = 4 waves (col split).
__global__ __launch_bounds__(256) void embed_ln_k(const float* __restrict__ ks,
                                                  const ushort* __restrict__ wH, const ushort* __restrict__ wL,
                                                  const float* __restrict__ pe_b, const float* __restrict__ cond_band,
                                                  const float* __restrict__ cond_rad, const float* __restrict__ cond_mask,
                                                  const float* __restrict__ mbuf,
                                                  const float* __restrict__ ln_g, const float* __restrict__ ln_b,
                                                  const float* __restrict__ fn_g, const float* __restrict__ fn_b,
                                                  float* __restrict__ h_,
                                                  ushort* __restrict__ hnH, ushort* __restrict__ hnL) {
    __shared__ __align__(16) char smem[41472];
    ushort (*AsH)[72] = (ushort(*)[72])(smem);             // 16x72
    ushort (*AsL)[72] = (ushort(*)[72])(smem + 2304);
    ushort (*BsH)[72] = (ushort(*)[72])(smem + 4608);      // 128x72
    ushort (*BsL)[72] = (ushort(*)[72])(smem + 23040);
    float  (*Cs)[132] = (float(*)[132])(smem);             // 16x132 (reuse)

    const int tid = threadIdx.x;
    const int lane = tid & 63, wn = tid >> 6;
    const int ln = lane & 15, q = lane >> 4;
    const int mb = blockIdx.x * 16;

    f32x4 acc[2];
    acc[0] = (f32x4){0.f, 0.f, 0.f, 0.f};
    acc[1] = (f32x4){0.f, 0.f, 0.f, 0.f};

    for (int kc = 0; kc < 128; kc += 64) {
        __syncthreads();
        // A: gather 16 x 64 from kspace
        for (int u = tid; u < 1024; u += 256) {
            int r = u >> 6, kk = u & 63;
            int l = mb + r, k = kc + kk;
            int cc = k >> 3, ijk = k & 7;
            int xg = l >> 8, yg = (l >> 3) & 31, zg = l & 7;
            int i2 = (ijk >> 2) & 1, j2 = (ijk >> 1) & 1, k2 = ijk & 1;
            float v = ks[cc * 65536 + (2 * xg + i2) * 1024 + (2 * yg + j2) * 16 + 2 * zg + k2];
            ushort h, lo; f2hl(v, &h, &lo);
            AsH[r][kk] = h; AsL[r][kk] = lo;
        }
        // B: pe 128 x 64
        for (int u = tid; u < 1024; u += 256) {
            int n = u >> 3, g = u & 7;
            *(uint4*)&BsH[n][g * 8] = *(const uint4*)&wH[W_PE + n * 128 + kc + g * 8];
            *(uint4*)&BsL[n][g * 8] = *(const uint4*)&wL[W_PE + n * 128 + kc + g * 8];
        }
        __syncthreads();
#pragma unroll
        for (int ks_ = 0; ks_ < 64; ks_ += 32) {
            const int kk = ks_ + q * 8;
            bf16x8 ah = *(const bf16x8*)&AsH[ln][kk];
            bf16x8 al = *(const bf16x8*)&AsL[ln][kk];
#pragma unroll
            for (int cb = 0; cb < 2; ++cb) {
                bf16x8 bh = *(const bf16x8*)&BsH[wn * 32 + cb * 16 + ln][kk];
                bf16x8 bl = *(const bf16x8*)&BsL[wn * 32 + cb * 16 + ln][kk];
                acc[cb] = __builtin_amdgcn_mfma_f32_16x16x32_bf16(ah, bh, acc[cb], 0, 0, 0);
                acc[cb] = __builtin_amdgcn_mfma_f32_16x16x32_bf16(ah, bl, acc[cb], 0, 0, 0);
                acc[cb] = __builtin_amdgcn_mfma_f32_16x16x32_bf16(al, bh, acc[cb], 0, 0, 0);
            }
        }
    }
    __syncthreads();
#pragma unroll
    for (int cb = 0; cb < 2; ++cb) {
#pragma unroll
        for (int r = 0; r < 4; ++r) {
            int row = q * 4 + r;
            int col = wn * 32 + cb * 16 + ln;
            int l = mb + row;
            float rho = (float)l * (1.0f / 8191.0f);
            int band = min(7, (int)(rho * 8.0f));
            Cs[row][col] = acc[cb][r] + pe_b[col] + cond_band[band * 128 + col]
                           + rho * cond_rad[col] + mbuf[l] * cond_mask[col];
        }
    }
    __syncthreads();
    {   // LN: 16 rows x 16 threads, 8 cols each
        int row = tid >> 4, j = tid & 15;
        int l = mb + row;
        float v8[8];
        float s = 0.f, s2 = 0.f;
#pragma unroll
        for (int i = 0; i < 8; ++i) {
            float v = Cs[row][j * 8 + i];
            v8[i] = v; s += v; s2 += v * v;
        }
#pragma unroll
        for (int o = 1; o < 16; o <<= 1) { s += __shfl_xor(s, o, 16); s2 += __shfl_xor(s2, o, 16); }
        float mu = s * (1.f / 128.f);
        float var = s2 * (1.f / 128.f) - mu * mu;
        float rstd = rsqrtf(fmaxf(var, 0.f) + 1e-5f);
        float hv[8];
        s = 0.f; s2 = 0.f;
#pragma unroll
        for (int i = 0; i < 8; ++i) {
            int col = j * 8 + i;
            float h = (v8[i] - mu) * rstd * ln_g[col] + ln_b[col];
            hv[i] = h; s += h; s2 += h * h;
        }
#pragma unroll
        for (int i = 0; i < 8; i += 4)
            *(float4*)&h_[(size_t)l * 128 + j * 8 + i] = make_float4(hv[i], hv[i + 1], hv[i + 2], hv[i + 3]);
#pragma unroll
        for (int o = 1; o < 16; o <<= 1) { s += __shfl_xor(s, o, 16); s2 += __shfl_xor(s2, o, 16); }
        mu = s * (1.f / 128.f);
        var = s2 * (1.f / 128.f) - mu * mu;
        rstd = rsqrtf(fmaxf(var, 0.f) + 1e-5f);
        union { ushort u[8]; uint4 v4; } oh, ol;
#pragma unroll
        for (int i = 0; i < 8; ++i) {
            int col = j * 8 + i;
            float o2 = (hv[i] - mu) * rstd * fn_g[col] + fn_b[col];
            ushort hh, ll; f2hl(o2, &hh, &ll);
            oh.u[i] = hh; ol.u[i] = ll;
        }
        *(uint4*)&hnH[(size_t)l * 128 + j * 8] = oh.v4;
        *(uint4*)&hnL[(size_t)l * 128 + j * 8] = ol.v4;
    }
}

// ---------------------------------------------------------------------------
// Win GEMM: 64x64 tiles, grid (128,8) = 1024 blocks. xp raw / sz silu split.
__global__ __launch_bounds__(256) void win_k(const ushort* __restrict__ Ah, const ushort* __restrict__ Al,
                                             const ushort* __restrict__ wH, const ushort* __restrict__ wL,
                                             const float* __restrict__ bin_,
                                             float* __restrict__ xp, float* __restrict__ sz) {
    __shared__ ushort AsH[64][72], AsL[64][72];
    __shared__ ushort BsH[64][72], BsL[64][72];
    const int tid = threadIdx.x;
    const int lane = tid & 63, wave = tid >> 6;
    const int wm = wave & 1, wn = wave >> 1;
    const int ln = lane & 15, q = lane >> 4;
    const int mb = blockIdx.x * 64, nb = blockIdx.y * 64;

    f32x4 acc[2][2];
#pragma unroll
    for (int rb = 0; rb < 2; ++rb)
#pragma unroll
        for (int cb = 0; cb < 2; ++cb) acc[rb][cb] = (f32x4){0.f, 0.f, 0.f, 0.f};

    for (int kc = 0; kc < 128; kc += 64) {
        __syncthreads();
        for (int u = tid; u < 512; u += 256) {
            int r = u >> 3, g = u & 7;
            size_t go = (size_t)(mb + r) * 128 + kc + g * 8;
            *(uint4*)&AsH[r][g * 8] = *(const uint4*)&Ah[go];
            *(uint4*)&AsL[r][g * 8] = *(const uint4*)&Al[go];
        }
        for (int u = tid; u < 512; u += 256) {
            int n = u >> 3, g = u & 7;
            size_t go = (size_t)(W_WIN) + (size_t)(nb + n) * 128 + kc + g * 8;
            *(uint4*)&BsH[n][g * 8] = *(const uint4*)&wH[go];
            *(uint4*)&BsL[n][g * 8] = *(const uint4*)&wL[go];
        }
        __syncthreads();
#pragma unroll
        for (int ks_ = 0; ks_ < 64; ks_ += 32) {
            const int kk = ks_ + q * 8;
            bf16x8 ah[2], al[2], bh[2], bl[2];
#pragma unroll
            for (int rb = 0; rb < 2; ++rb) {
                ah[rb] = *(const bf16x8*)&AsH[wm * 32 + rb * 16 + ln][kk];
                al[rb] = *(const bf16x8*)&AsL[wm * 32 + rb * 16 + ln][kk];
            }
#pragma unroll
            for (int cb = 0; cb < 2; ++cb) {
                bh[cb] = *(const bf16x8*)&BsH[wn * 32 + cb * 16 + ln][kk];
                bl[cb] = *(const bf16x8*)&BsL[wn * 32 + cb * 16 + ln][kk];
            }
#pragma unroll
            for (int rb = 0; rb < 2; ++rb)
#pragma unroll
                for (int cb = 0; cb < 2; ++cb) {
                    acc[rb][cb] = __builtin_amdgcn_mfma_f32_16x16x32_bf16(ah[rb], bh[cb], acc[rb][cb], 0, 0, 0);
                    acc[rb][cb] = __builtin_amdgcn_mfma_f32_16x16x32_bf16(ah[rb], bl[cb], acc[rb][cb], 0, 0, 0);
                    acc[rb][cb] = __builtin_amdgcn_mfma_f32_16x16x32_bf16(al[rb], bh[cb], acc[rb][cb], 0, 0, 0);
                }
        }
    }
#pragma unroll
    for (int rb = 0; rb < 2; ++rb)
#pragma unroll
        for (int cb = 0; cb < 2; ++cb)
#pragma unroll
            for (int r = 0; r < 4; ++r) {
                int l = mb + wm * 32 + rb * 16 + q * 4 + r;
                int col = nb + wn * 32 + cb * 16 + ln;
                float v = acc[rb][cb][r] + bin_[col];
                if (col < 256) {
                    xp[(size_t)l * 256 + col] = v;
                } else {
                    sz[(size_t)l * 256 + (col - 256)] = v * sigm(v);
                }
            }
}

// causal depthwise conv (4 taps) + SiLU, float4 over channels
__global__ __launch_bounds__(256) void conv_k(const float* __restrict__ xp, const float* __restrict__ convw,
                                              const float* __restrict__ convb, float* __restrict__ xc) {
    int id = blockIdx.x * 256 + threadIdx.x;   // < 524288
    int l = id >> 6, e4 = (id & 63) * 4;
    float4 cw[4];
#pragma unroll
    for (int j = 0; j < 4; ++j) cw[j] = *(const float4*)&convw[(e4 + j) * 4];
    float4 cb = *(const float4*)&convb[e4];
    float o[4] = {cb.x, cb.y, cb.z, cb.w};
#pragma unroll
    for (int k = 0; k < 4; ++k) {
        int lp = l - 3 + k;
        if (lp >= 0) {
            float4 t = *(const float4*)&xp[(size_t)lp * 256 + e4];
            o[0] += t.x * ((const float*)&cw[0])[k];
            o[1] += t.y * ((const float*)&cw[1])[k];
            o[2] += t.z * ((const float*)&cw[2])[k];
            o[3] += t.w * ((const float*)&cw[3])[k];
        }
    }
    float4 r;
    r.x = o[0] * sigm(o[0]);
    r.y = o[1] * sigm(o[1]);
    r.z = o[2] * sigm(o[2]);
    r.w = o[3] * sigm(o[3]);
    *(float4*)&xc[(size_t)l * 256 + e4] = r;
}

// ---------------------------------------------------------------------------
// proj GEMM: 64x64 tiles, grid (128,5). epilogue -> dt / Bm / Cm
__global__ __launch_bounds__(256) void proj_k(const float* __restrict__ xc,
                                              const ushort* __restrict__ wH, const ushort* __restrict__ wL,
                                              const float* __restrict__ bdt, const float* __restrict__ mbuf,
                                              const float* __restrict__ edt, const float* __restrict__ eB,
                                              const float* __restrict__ eC, const float* __restrict__ wr,
                                              const float* __restrict__ wm,
                                              float* __restrict__ dt, float* __restrict__ Bm, float* __restrict__ Cm) {
    __shared__ ushort AsH[64][72], AsL[64][72];
    __shared__ ushort BsH[64][72], BsL[64][72];
    const int tid = threadIdx.x;
    const int lane = tid & 63, wave = tid >> 6;
    const int wm_ = wave & 1, wn = wave >> 1;
    const int ln = lane & 15, q = lane >> 4;
    const int mb = blockIdx.x * 64, nb = blockIdx.y * 64;

    f32x4 acc[2][2];
#pragma unroll
    for (int rb = 0; rb < 2; ++rb)
#pragma unroll
        for (int cb = 0; cb < 2; ++cb) acc[rb][cb] = (f32x4){0.f, 0.f, 0.f, 0.f};

    for (int kc = 0; kc < 256; kc += 64) {
        __syncthreads();
        for (int u = tid; u < 1024; u += 256) {
            int r = u >> 4, kq = u & 15;
            float4 v = *(const float4*)&xc[(size_t)(mb + r) * 256 + kc + kq * 4];
            union { ushort u[4]; uint2 v2; } hh, ll;
            f2hl(v.x, &hh.u[0], &ll.u[0]); f2hl(v.y, &hh.u[1], &ll.u[1]);
            f2hl(v.z, &hh.u[2], &ll.u[2]); f2hl(v.w, &hh.u[3], &ll.u[3]);
            *(uint2*)&AsH[r][kq * 4] = hh.v2;
            *(uint2*)&AsL[r][kq * 4] = ll.v2;
        }
        for (int u = tid; u < 512; u += 256) {
            int n = u >> 3, g = u & 7;
            size_t go = (size_t)(W_PROJ) + (size_t)(nb + n) * 256 + kc + g * 8;
            *(uint4*)&BsH[n][g * 8] = *(const uint4*)&wH[go];
            *(uint4*)&BsL[n][g * 8] = *(const uint4*)&wL[go];
        }
        __syncthreads();
#pragma unroll
        for (int ks_ = 0; ks_ < 64; ks_ += 32) {
            const int kk = ks_ + q * 8;
            bf16x8 ah[2], al[2], bh[2], bl[2];
#pragma unroll
            for (int rb = 0; rb < 2; ++rb) {
                ah[rb] = *(const bf16x8*)&AsH[wm_ * 32 + rb * 16 + ln][kk];
                al[rb] = *(const bf16x8*)&AsL[wm_ * 32 + rb * 16 + ln][kk];
            }
#pragma unroll
            for (int cb = 0; cb < 2; ++cb) {
                bh[cb] = *(const bf16x8*)&BsH[wn * 32 + cb * 16 + ln][kk];
                bl[cb] = *(const bf16x8*)&BsL[wn * 32 + cb * 16 + ln][kk];
            }
#pragma unroll
            for (int rb = 0; rb < 2; ++rb)
#pragma unroll
                for (int cb = 0; cb < 2; ++cb) {
                    acc[rb][cb] = __builtin_amdgcn_mfma_f32_16x16x32_bf16(ah[rb], bh[cb], acc[rb][cb], 0, 0, 0);
                    acc[rb][cb] = __builtin_amdgcn_mfma_f32_16x16x32_bf16(ah[rb], bl[cb], acc[rb][cb], 0, 0, 0);
                    acc[rb][cb] = __builtin_amdgcn_mfma_f32_16x16x32_bf16(al[rb], bh[cb], acc[rb][cb], 0, 0, 0);
                }
        }
    }
#pragma unroll
    for (int rb = 0; rb < 2; ++rb)
#pragma unroll
        for (int cb = 0; cb < 2; ++cb)
#pragma unroll
            for (int r = 0; r < 4; ++r) {
                int l = mb + wm_ * 32 + rb * 16 + q * 4 + r;
                int col = nb + wn * 32 + cb * 16 + ln;
                float v = acc[rb][cb][r];
                float rho = (float)l * (1.0f / 8191.0f);
                int band = min(7, (int)(rho * 8.0f));
                float mv = mbuf[l];
                if (col < 256) {
                    float sc0 = 2.0f * sigm(edt[band] + wr[0] * rho + wm[0] * mv);
                    float v2 = v + bdt[col];
                    float sp = (v2 > 20.f) ? v2 : log1pf(expf(v2));
                    dt[(size_t)l * 256 + col] = sp * sc0;
                } else if (col < 272) {
                    float sc1 = 2.0f * sigm(eB[band] + wr[1] * rho + wm[1] * mv);
                    Bm[(size_t)l * 16 + (col - 256)] = v * sc1;
                } else if (col < 288) {
                    float sc2 = 2.0f * sigm(eC[band] + wr[2] * rho + wm[2] * mv);
                    Cm[(size_t)l * 16 + (col - 272)] = v * sc2;
                }
            }
}

// ---------------------------------------------------------------------------
// scan, one lane per channel e, h[16] in registers; 8-step batched prefetch.
template <int PHASE>
__global__ __launch_bounds__(256) void scan_k(const float* __restrict__ dt, const float* __restrict__ xc,
                                              const float* __restrict__ Bm, const float* __restrict__ Cm,
                                              const float* __restrict__ Alog,
                                              float* __restrict__ Hb, float* __restrict__ sdtb,
                                              float* __restrict__ yf, float* __restrict__ yb) {
    const int c = blockIdx.x, dir = blockIdx.y, e = threadIdx.x;
    __shared__ float bms[CLh][16];
    __shared__ float cms[CLh][16];
    for (int idx = e; idx < CLh * 16; idx += 256) {
        bms[idx >> 4][idx & 15] = Bm[c * (CLh * 16) + idx];
        if (PHASE == 1) cms[idx >> 4][idx & 15] = Cm[c * (CLh * 16) + idx];
    }
    float A2[16], iv[16], h[16];
#pragma unroll
    for (int n = 0; n < 16; ++n) {
        float ea = nexp2(Alog[e * 16 + n] * LOG2E);   // = exp(Alog)
        A2[n] = -ea * LOG2E;
        iv[n] = -1.0f / ea;                           // 1/A
    }
    const size_t hofs = (size_t)(dir * NCh + c) * 4096 + e * 16;
    if (PHASE == 0) {
#pragma unroll
        for (int n = 0; n < 16; ++n) h[n] = 0.f;
    } else {
#pragma unroll
        for (int j = 0; j < 4; ++j) {
            float4 hv = *(const float4*)&Hb[hofs + 4 * j];
            h[4 * j] = hv.x; h[4 * j + 1] = hv.y; h[4 * j + 2] = hv.z; h[4 * j + 3] = hv.w;
        }
    }
    const int base = c * CLh;
    float cu[8], cx[8], nu[8], nx[8];
#pragma unroll
    for (int j = 0; j < 8; ++j) {
        int p = dir ? (CLh - 1 - j) : j;
        cu[j] = dt[(size_t)(base + p) * 256 + e];
        cx[j] = xc[(size_t)(base + p) * 256 + e];
    }
    __syncthreads();
    float sdt = 0.f;
    float* __restrict__ yp = dir ? yb : yf;
#pragma unroll
    for (int g = 0; g < CLh / 8; ++g) {
        if (g + 1 < CLh / 8) {
#pragma unroll
            for (int j = 0; j < 8; ++j) {
                int s = (g + 1) * 8 + j;
                int p = dir ? (CLh - 1 - s) : s;
                nu[j] = dt[(size_t)(base + p) * 256 + e];
                nx[j] = xc[(size_t)(base + p) * 256 + e];
            }
        }
#pragma unroll
        for (int j = 0; j < 8; ++j) {
            int s = g * 8 + j;
            int p = dir ? (CLh - 1 - s) : s;
            float u = cu[j], xv = cx[j];
            union { float4 v[4]; float f[16]; } bb, cc;
            const float4* bp = (const float4*)&bms[p][0];
            bb.v[0] = bp[0]; bb.v[1] = bp[1]; bb.v[2] = bp[2]; bb.v[3] = bp[3];
            if (PHASE == 1) {
                const float4* cp = (const float4*)&cms[p][0];
                cc.v[0] = cp[0]; cc.v[1] = cp[1]; cc.v[2] = cp[2]; cc.v[3] = cp[3];
            }
            float y = 0.f;
#pragma unroll
            for (int n = 0; n < 16; ++n) {
                float a = nexp2(A2[n] * u);
                float w = xv * bb.f[n] * iv[n];
                float t = h[n] + w;
                h[n] = a * t - w;
                if (PHASE == 1) y += h[n] * cc.f[n];
            }
            if (PHASE == 0) sdt += u;
            if (PHASE == 1) yp[(size_t)(base + p) * 256 + e] = y;
        }
#pragma unroll
        for (int j = 0; j < 8; ++j) { cu[j] = nu[j]; cx[j] = nx[j]; }
    }
    if (PHASE == 0) {
#pragma unroll
        for (int j = 0; j < 4; ++j) {
            float4 hv = make_float4(h[4 * j], h[4 * j + 1], h[4 * j + 2], h[4 * j + 3]);
            *(float4*)&Hb[hofs + 4 * j] = hv;
        }
        if (dir == 0) sdtb[c * 256 + e] = sdt;
    }
}

// chunk-level scan: Hpre[c] <- prefix state entering chunk c (reads Hb, no alias)
__global__ __launch_bounds__(64) void combine_k(const float* __restrict__ Hb, float* __restrict__ Hpre,
                                                const float* __restrict__ sdtb, const float* __restrict__ Alog) {
    int id = blockIdx.x * 64 + threadIdx.x;   // < 8192
    int dir = id >> 12, en = id & 4095, e = en >> 4;
    float A2 = -nexp2(Alog[en] * LOG2E) * LOG2E;
    float hi = 0.f;
    for (int g = 0; g < NCh / 8; ++g) {
        float Pv[8], qv[8];
#pragma unroll
        for (int j = 0; j < 8; ++j) {
            int c = dir ? (NCh - 1 - (g * 8 + j)) : (g * 8 + j);
            Pv[j] = sdtb[c * 256 + e];
            qv[j] = Hb[(size_t)(dir * NCh + c) * 4096 + en];
        }
#pragma unroll
        for (int j = 0; j < 8; ++j) {
            int c = dir ? (NCh - 1 - (g * 8 + j)) : (g * 8 + j);
            float P = nexp2(A2 * Pv[j]);
            Hpre[(size_t)(dir * NCh + c) * 4096 + en] = hi;
            hi = P * hi + qv[j];
        }
    }
}

// ---------------------------------------------------------------------------
// Wout GEMM with gate fused in A-staging: 32x64 tiles, grid (256,2).
__global__ __launch_bounds__(256) void wout_k(const float* __restrict__ yf, const float* __restrict__ yb,
                                              const float* __restrict__ xc, const float* __restrict__ sz,
                                              const float* __restrict__ Dp,
                                              const ushort* __restrict__ wH, const ushort* __restrict__ wL,
                                              const float* __restrict__ bout, const float* __restrict__ h_,
                                              ushort* __restrict__ hfH, ushort* __restrict__ hfL) {
    __shared__ ushort AsH[32][72], AsL[32][72];
    __shared__ ushort BsH[64][72], BsL[64][72];
    const int tid = threadIdx.x;
    const int lane = tid & 63, wave = tid >> 6;
    const int wm = wave & 1, wn = wave >> 1;
    const int ln = lane & 15, q = lane >> 4;
    const int mb = blockIdx.x * 32, nb = blockIdx.y * 64;

    f32x4 acc[2];
    acc[0] = (f32x4){0.f, 0.f, 0.f, 0.f};
    acc[1] = (f32x4){0.f, 0.f, 0.f, 0.f};

    for (int kc = 0; kc < 256; kc += 64) {
        __syncthreads();
        for (int u = tid; u < 512; u += 256) {
            int r = u >> 4, kq = u & 15;
            size_t go = (size_t)(mb + r) * 256 + kc + kq * 4;
            float4 a = *(const float4*)&yf[go];
            float4 b = *(const float4*)&yb[go];
            float4 x = *(const float4*)&xc[go];
            float4 s = *(const float4*)&sz[go];
            float4 d = *(const float4*)&Dp[kc + kq * 4];
            float v0 = (a.x + b.x + d.x * x.x) * s.x;
            float v1 = (a.y + b.y + d.y * x.y) * s.y;
            float v2 = (a.z + b.z + d.z * x.z) * s.z;
            float v3 = (a.w + b.w + d.w * x.w) * s.w;
            union { ushort u[4]; uint2 v2; } hh, ll;
            f2hl(v0, &hh.u[0], &ll.u[0]); f2hl(v1, &hh.u[1], &ll.u[1]);
            f2hl(v2, &hh.u[2], &ll.u[2]); f2hl(v3, &hh.u[3], &ll.u[3]);
            *(uint2*)&AsH[r][kq * 4] = hh.v2;
            *(uint2*)&AsL[r][kq * 4] = ll.v2;
        }
        for (int u = tid; u < 512; u += 256) {
            int n = u >> 3, g = u & 7;
            size_t go = (size_t)(W_WOUT) + (size_t)(nb + n) * 256 + kc + g * 8;
            *(uint4*)&BsH[n][g * 8] = *(const uint4*)&wH[go];
            *(uint4*)&BsL[n][g * 8] = *(const uint4*)&wL[go];
        }
        __syncthreads();
#pragma unroll
        for (int ks_ = 0; ks_ < 64; ks_ += 32) {
            const int kk = ks_ + q * 8;
            bf16x8 ah = *(const bf16x8*)&AsH[wm * 16 + ln][kk];
            bf16x8 al = *(const bf16x8*)&AsL[wm * 16 + ln][kk];
#pragma unroll
            for (int cb = 0; cb < 2; ++cb) {
                bf16x8 bh = *(const bf16x8*)&BsH[wn * 32 + cb * 16 + ln][kk];
                bf16x8 bl = *(const bf16x8*)&BsL[wn * 32 + cb * 16 + ln][kk];
                acc[cb] = __builtin_amdgcn_mfma_f32_16x16x32_bf16(ah, bh, acc[cb], 0, 0, 0);
                acc[cb] = __builtin_amdgcn_mfma_f32_16x16x32_bf16(ah, bl, acc[cb], 0, 0, 0);
                acc[cb] = __builtin_amdgcn_mfma_f32_16x16x32_bf16(al, bh, acc[cb], 0, 0, 0);
            }
        }
    }
#pragma unroll
    for (int cb = 0; cb < 2; ++cb)
#pragma unroll
        for (int r = 0; r < 4; ++r) {
            int l = mb + wm * 16 + q * 4 + r;
            int col = nb + wn * 32 + cb * 16 + ln;
            float v = acc[cb][r] + bout[col] + h_[(size_t)l * 128 + col];
            ushort hh, ll; f2hl(v, &hh, &ll);
            hfH[(size_t)l * 128 + col] = hh;
            hfL[(size_t)l * 128 + col] = ll;
        }
}

// unembed GEMM: 32x64 tiles, grid (256,2); out = hf @ pu^T + pu_b + ks (scattered)
__global__ __launch_bounds__(256) void unembed_k(const ushort* __restrict__ Ah, const ushort* __restrict__ Al,
                                                 const ushort* __restrict__ wH, const ushort* __restrict__ wL,
                                                 const float* __restrict__ pu_b, const float* __restrict__ ks,
                                                 float* __restrict__ out) {
    __shared__ ushort AsH[32][72], AsL[32][72];
    __shared__ ushort BsH[64][72], BsL[64][72];
    const int tid = threadIdx.x;
    const int lane = tid & 63, wave = tid >> 6;
    const int wm = wave & 1, wn = wave >> 1;
    const int ln = lane & 15, q = lane >> 4;
    const int mb = blockIdx.x * 32, nb = blockIdx.y * 64;

    f32x4 acc[2];
    acc[0] = (f32x4){0.f, 0.f, 0.f, 0.f};
    acc[1] = (f32x4){0.f, 0.f, 0.f, 0.f};

    for (int kc = 0; kc < 128; kc += 64) {
        __syncthreads();
        for (int u = tid; u < 256; u += 256) {
            int r = u >> 3, g = u & 7;
            size_t go = (size_t)(mb + r) * 128 + kc + g * 8;
            *(uint4*)&AsH[r][g * 8] = *(const uint4*)&Ah[go];
            *(uint4*)&AsL[r][g * 8] = *(const uint4*)&Al[go];
        }
        for (int u = tid; u < 512; u += 256) {
            int n = u >> 3, g = u & 7;
            size_t go = (size_t)(W_PU) + (size_t)(nb + n) * 128 + kc + g * 8;
            *(uint4*)&BsH[n][g * 8] = *(const uint4*)&wH[go];
            *(uint4*)&BsL[n][g * 8] = *(const uint4*)&wL[go];
        }
        __syncthreads();
#pragma unroll
        for (int ks_ = 0; ks_ < 64; ks_ += 32) {
            const int kk = ks_ + q * 8;
            bf16x8 ah = *(const bf16x8*)&AsH[wm * 16 + ln][kk];
            bf16x8 al = *(const bf16x8*)&AsL[wm * 16 + ln][kk];
#pragma unroll
            for (int cb = 0; cb < 2; ++cb) {
                bf16x8 bh = *(const bf16x8*)&BsH[wn * 32 + cb * 16 + ln][kk];
                bf16x8 bl = *(const bf16x8*)&BsL[wn * 32 + cb * 16 + ln][kk];
                acc[cb] = __builtin_amdgcn_mfma_f32_16x16x32_bf16(ah, bh, acc[cb], 0, 0, 0);
                acc[cb] = __builtin_amdgcn_mfma_f32_16x16x32_bf16(ah, bl, acc[cb], 0, 0, 0);
                acc[cb] = __builtin_amdgcn_mfma_f32_16x16x32_bf16(al, bh, acc[cb], 0, 0, 0);
            }
        }
    }
#pragma unroll
    for (int cb = 0; cb < 2; ++cb)
#pragma unroll
        for (int r = 0; r < 4; ++r) {
            int l = mb + wm * 16 + q * 4 + r;
            int col = nb + wn * 32 + cb * 16 + ln;
            int xg = l >> 8, yg = (l >> 3) & 31, zg = l & 7;
            int c = col >> 3, ijk = col & 7;
            int i2 = (ijk >> 2) & 1, j2 = (ijk >> 1) & 1, k2 = ijk & 1;
            size_t idx = (size_t)((c * 64 + 2 * xg + i2) * 64 + (2 * yg + j2)) * 16 + 2 * zg + k2;
            out[idx] = acc[cb][r] + pu_b[c] + ks[idx];
        }
}

// ---------------------------------------------------------------------------
extern "C" void kernel_launch(void* const* d_in, const int* in_sizes, int n_in,
                              void* d_out, int out_size, void* d_ws, size_t ws_size,
                              hipStream_t stream) {
    const float* ks    = (const float*)d_in[0];
    const float* mask  = (const float*)d_in[1];
    const float* pe_w  = (const float*)d_in[2];
    const float* pe_b  = (const float*)d_in[3];
    const float* pu_w  = (const float*)d_in[4];
    const float* pu_b  = (const float*)d_in[5];
    const float* ln_g  = (const float*)d_in[6];
    const float* ln_b  = (const float*)d_in[7];
    const float* fn_g  = (const float*)d_in[8];
    const float* fn_b  = (const float*)d_in[9];
    const float* cond_band = (const float*)d_in[10];
    const float* cond_rad  = (const float*)d_in[11];
    const float* cond_mask = (const float*)d_in[12];
    const float* Win   = (const float*)d_in[13];
    const float* bin_  = (const float*)d_in[14];
    const float* convw = (const float*)d_in[15];
    const float* convb = (const float*)d_in[16];
    const float* Wx    = (const float*)d_in[17];
    const float* Wdt   = (const float*)d_in[18];
    const float* bdt   = (const float*)d_in[19];
    const float* Alog  = (const float*)d_in[20];
    const float* Dp    = (const float*)d_in[21];
    const float* Wout  = (const float*)d_in[22];
    const float* bout  = (const float*)d_in[23];
    const float* edt   = (const float*)d_in[24];
    const float* eB    = (const float*)d_in[25];
    const float* eC    = (const float*)d_in[26];
    const float* wr    = (const float*)d_in[27];
    const float* wm    = (const float*)d_in[28];
    float* out = (float*)d_out;

    char* base = (char*)d_ws;
    size_t o = 0;
    auto alloc = [&](size_t bytes) { char* p = base + o; o += (bytes + 255) & ~(size_t)255; return p; };
    float*  mbuf = (float*)alloc(32768);
    ushort* wH   = (ushort*)alloc(W_TOT * 2);
    ushort* wL   = (ushort*)alloc(W_TOT * 2);
    float*  h_   = (float*)alloc(4194304);
    ushort* hnH  = (ushort*)alloc(2097152);
    ushort* hnL  = (ushort*)alloc(2097152);
    float*  xp   = (float*)alloc(8388608);
    float*  sz   = (float*)alloc(8388608);
    float*  xc   = (float*)alloc(8388608);
    float*  dt   = (float*)alloc(8388608);
    float*  Bm   = (float*)alloc(524288);
    float*  Cm   = (float*)alloc(524288);
    float*  Hb   = (float*)alloc(8388608);
    float*  Hpre = (float*)alloc(8388608);
    float*  sdtb = (float*)alloc(262144);
    float*  yf   = (float*)alloc(8388608);
    float*  yb   = (float*)alloc(8388608);
    ushort* hfH  = (ushort*)alloc(2097152);
    ushort* hfL  = (ushort*)alloc(2097152);

    prep_k<<<864, 256, 0, stream>>>(pe_w, Win, Wx, Wdt, Wout, pu_w, mask, wH, wL, mbuf);
    embed_ln_k<<<512, 256, 0, stream>>>(ks, wH, wL, pe_b, cond_band, cond_rad, cond_mask, mbuf,
                                        ln_g, ln_b, fn_g, fn_b, h_, hnH, hnL);
    win_k<<<dim3(128, 8), 256, 0, stream>>>(hnH, hnL, wH, wL, bin_, xp, sz);
    conv_k<<<2048, 256, 0, stream>>>(xp, convw, convb, xc);
    proj_k<<<dim3(128, 5), 256, 0, stream>>>(xc, wH, wL, bdt, mbuf, edt, eB, eC, wr, wm, dt, Bm, Cm);
    scan_k<0><<<dim3(NCh, 2), 256, 0, stream>>>(dt, xc, Bm, Cm, Alog, Hb, sdtb, nullptr, nullptr);
    combine_k<<<128, 64, 0, stream>>>(Hb, Hpre, sdtb, Alog);
    scan_k<1><<<dim3(NCh, 2), 256, 0, stream>>>(dt, xc, Bm, Cm, Alog, Hpre, sdtb, yf, yb);
    wout_k<<<dim3(256, 2), 256, 0, stream>>>(yf, yb, xc, sz, Dp, wH, wL, bout, h_, hfH, hfL);
    unembed_k<<<dim3(256, 2), 256, 0, stream>>>(hfH, hfL, wH, wL, pu_b, ks, out);
}